// Round 12
// baseline (995.692 us; speedup 1.0000x reference)
//
#include <hip/hip_runtime.h>

#define NBLK 256
#define NTHR 1024                // 16 waves = 4/SIMD: TLP hides L2 latency; 128-reg/wave cap
#define MTILE 32
#define KPADI 592                // abuf row stride bytes (16-aligned)
#define HSTR  528                // hsave row stride bytes
#define CHB   (9*8*64*16)        // 73728 bytes per 16-col chunk per LSTM (9 k-tiles of K=64)
#define LSTR  (16*CHB)           // 1179648 bytes per LSTM

typedef __attribute__((ext_vector_type(4))) int int4v;

__device__ inline float ex2(float x){ return __builtin_amdgcn_exp2f(x); }
__device__ inline float rcpf_(float d){ return __builtin_amdgcn_rcpf(d); }
__device__ inline float rcpn(float d){ float r=__builtin_amdgcn_rcpf(d); return r*(2.f-d*r); }
#define LOG2E 1.4426950408889634f
__device__ inline float tanh_(float x){ return 2.f*rcpf_(1.f+ex2(-2.f*LOG2E*x))-1.f; }

// ---- per-LSTM scale: max(|Whh|, |Wih|, |bih+bhh|/2), via atomicMax on float bits.
__global__ void scale_k(const float* Ws_ih, const float* Ws_hh, const float* bs_ih, const float* bs_hh,
                        const float* Wp_ih, const float* Wp_hh, const float* bp_ih, const float* bp_hh,
                        const float* Wd_ih, const float* Wd_hh, const float* bd_ih, const float* bd_hh,
                        int* smax)
{
    int L = blockIdx.x >> 5;
    int blk = blockIdx.x & 31;
    const float* Wih = L==0 ? Ws_ih : L==1 ? Wp_ih : Wd_ih;
    const float* Whh = L==0 ? Ws_hh : L==1 ? Wp_hh : Wd_hh;
    const float* bih = L==0 ? bs_ih : L==1 ? bp_ih : bd_ih;
    const float* bhh = L==0 ? bs_hh : L==1 ? bp_hh : bd_hh;
    float m = 0.f;
    for (int i = blk*256 + threadIdx.x; i < 2048*512; i += 32*256) m = fmaxf(m, fabsf(Whh[i]));
    for (int i = blk*256 + threadIdx.x; i < 2048*4;   i += 32*256) m = fmaxf(m, fabsf(Wih[i]));
    for (int i = blk*256 + threadIdx.x; i < 2048;     i += 32*256) m = fmaxf(m, 0.5f*fabsf(bih[i]+bhh[i]));
    __shared__ float red[256];
    red[threadIdx.x] = m; __syncthreads();
    for (int s = 128; s; s >>= 1){
        if (threadIdx.x < s) red[threadIdx.x] = fmaxf(red[threadIdx.x], red[threadIdx.x+s]);
        __syncthreads();
    }
    if (threadIdx.x == 0) atomicMax(&smax[L], __float_as_int(red[0]));
}

// Pack: BP[chunk(16)][kt(9)][nt(8)][lane(64)][16 i8]; element B[k][n]:
// n=(chunk*8+nt)*16+(lane&15), k=kt*64+(lane>>4)*16+j. Packed n decode: ch=n>>7,
// g=(n>>5)&3, u=n&31 -> row=g*512+ch*32+u. K rows: 0..511=Whh; 512..527=Wih
// x-replicas (A holds x/4, 4 copies per dim); 528..529=(b_ih+b_hh)/2 (A holds 127);
// 530..575=0.  Gate order per chunk: nt 0,1=i 2,3=f 4,5=g 6,7=o (up=nt&1).
__global__ void pack_k(const float* Wih, const float* Whh, const float* bih, const float* bhh,
                       const int* smax, int L, unsigned char* dst, float* gsout)
{
    int f4 = blockIdx.x*256 + threadIdx.x;
    if (f4*4 >= LSTR) return;
    float mx = __int_as_float(smax[L]);
    float inv = 127.f / mx;
    if (blockIdx.x==0 && threadIdx.x==0) gsout[L] = mx * (1.f/(127.f*127.f));
    int fb = f4*4;
    int lane=(fb>>4)&63, nt=(fb>>10)&7, t=fb>>13;
    int kt=t%9, chunk=t/9;
    int n = (chunk*8+nt)*16 + (lane&15);
    int ch=n>>7, g=(n>>5)&3, u=n&31;
    int row = g*512 + ch*32 + u;
    int kbase = kt*64 + ((lane>>4)<<4) + (fb&15);
    unsigned out = 0;
    #pragma unroll
    for (int b=0;b<4;++b){
        int k = kbase + b;
        float v = 0.f;
        if (k < 512)      v = Whh[row*512+k];
        else if (k < 528) v = Wih[row*4 + (k&3)];
        else if (k < 530) v = 0.5f*(bih[row]+bhh[row]);
        int q = (int)rintf(v*inv);
        q = q>127?127:(q<-127?-127:q);
        out |= ((unsigned)(q & 255)) << (8*b);
    }
    *(unsigned*)(dst + fb) = out;
}

__global__ __launch_bounds__(NTHR, 1)
void lstm_all(const float* __restrict__ speed, const float* __restrict__ pos,
              const unsigned char* __restrict__ wpack, const float* __restrict__ gsb,
              const float* __restrict__ wfc, const float* __restrict__ bfc,
              const float* __restrict__ wemb, const float* __restrict__ bemb,
              float* __restrict__ out)
{
    __shared__ __align__(16) unsigned char abuf[2][MTILE][KPADI];  // 37888 B
    __shared__ __align__(16) unsigned char hsave[MTILE][HSTR];     // 16896 B
    __shared__ float csave[MTILE][512];                            // 65536 B
    __shared__ float smallw[1040];                                 // 4160 B
    __shared__ float partial[NTHR];                                // 4096 B

    const int tid  = threadIdx.x;
    const int lane = tid & 63;
    const int wv   = tid >> 6;          // 0..15; wave owns chunk (wv+cstag)&15
    const int row0 = blockIdx.x * MTILE;
    const int l15  = lane & 15;
    const int lq   = lane >> 4;
    const int cstag = blockIdx.x & 15;  // chunk stagger across blocks
    const int ch   = (wv + cstag) & 15;

    const float gs0 = gsb[0], gs1 = gsb[1], gs2 = gsb[2];

    // ---- init LDS ----
    {
        for (int i = tid; i < 2*MTILE*(KPADI/16); i += NTHR) {
            int b = i / (MTILE*(KPADI/16));
            int rmd = i % (MTILE*(KPADI/16));
            int m = rmd / (KPADI/16), c16 = (rmd % (KPADI/16))*16;
            *(int4v*)&abuf[b][m][c16] = (int4v){0,0,0,0};
        }
        for (int i = tid; i < 1024; i += NTHR) smallw[i] = wfc[i];
        if (tid < 2) smallw[1024+tid] = bfc[tid];
        if (tid < 8) smallw[1026+tid] = wemb[tid];
        if (tid < 4) smallw[1034+tid] = bemb[tid];
    }
    __syncthreads();
    if (tid < 64) { int b = tid>>5, m = tid&31; abuf[b][m][528] = 127; abuf[b][m][529] = 127; }
    if (tid < 128) {
        int m = tid>>2, f3 = tid&3;
        float x = speed[((size_t)(row0+m)*16 + 0)*4 + f3];
        int q = (int)rintf(fminf(fmaxf(x*31.75f,-127.f),127.f));
        unsigned char qb = (unsigned char)q;
        abuf[0][m][512+f3]=qb; abuf[0][m][516+f3]=qb; abuf[0][m][520+f3]=qb; abuf[0][m][524+f3]=qb;
    }
    __syncthreads();

    float cc[16];
    #pragma unroll
    for (int i = 0; i < 16; ++i) cc[i]=0.f;

    // One cell step for this wave's chunk (128 gate-cols = 32 hidden), M=32 rows.
    // Gates split: half0 = i,f (nt0-3) -> sI + c*=sig(f); half1 = g,o (nt4-7).
    // acc[2][4] + bA[4]/bB[4] keeps the wave under the 128-reg cap at 4 waves/SIMD.
    auto pass = [&](int rb, int wbuf, const unsigned char* wl,
                    float nK1, float nK2, int DUAL, int DEFER, int (&hq)[16]) {
        const unsigned char* bp0 = wl + (size_t)ch*CHB + lane*16;   // nt 0-3
        const unsigned char* bp1 = bp0 + 4*1024;                    // nt 4-7
        const unsigned char* ar0 = &abuf[rb][l15][0];
        const unsigned char* ar1 = &abuf[rb][16+l15][0];
        float sI[16];
        int4v bA[4], bB[4], acc[2][4];
        // ================= half 0: i,f =================
        #pragma unroll
        for (int j=0;j<4;++j) bA[j] = *(const int4v*)(bp0 + j*1024);
        #pragma unroll
        for (int mf=0;mf<2;++mf)
            #pragma unroll
            for (int j=0;j<4;++j) acc[mf][j] = (int4v){0,0,0,0};
        #pragma unroll 1
        for (int kt=0; kt<8; kt+=2){
            const unsigned char* p1 = bp0 + (kt+1)*8192;
            #pragma unroll
            for (int j=0;j<4;++j) bB[j] = *(const int4v*)(p1 + j*1024);
            int4v a0 = *(const int4v*)(ar0 + kt*64 + lq*16);
            int4v a1 = *(const int4v*)(ar1 + kt*64 + lq*16);
            #pragma unroll
            for (int j=0;j<4;++j){
                acc[0][j] = __builtin_amdgcn_mfma_i32_16x16x64_i8(a0, bA[j], acc[0][j], 0,0,0);
                acc[1][j] = __builtin_amdgcn_mfma_i32_16x16x64_i8(a1, bA[j], acc[1][j], 0,0,0);
            }
            const unsigned char* p2 = bp0 + (kt+2)*8192;
            #pragma unroll
            for (int j=0;j<4;++j) bA[j] = *(const int4v*)(p2 + j*1024);
            a0 = *(const int4v*)(ar0 + (kt+1)*64 + lq*16);
            a1 = *(const int4v*)(ar1 + (kt+1)*64 + lq*16);
            #pragma unroll
            for (int j=0;j<4;++j){
                acc[0][j] = __builtin_amdgcn_mfma_i32_16x16x64_i8(a0, bB[j], acc[0][j], 0,0,0);
                acc[1][j] = __builtin_amdgcn_mfma_i32_16x16x64_i8(a1, bB[j], acc[1][j], 0,0,0);
            }
        }
        // bA = tile8; bB dead -> prefetch half1 tile0 (hides under epilogue0)
        #pragma unroll
        for (int j=0;j<4;++j) bB[j] = *(const int4v*)(bp1 + j*1024);
        {   // kt=8 tail: ALL accs use bA (x/bias tile)
            int4v a0 = *(const int4v*)(ar0 + 8*64 + lq*16);
            int4v a1 = *(const int4v*)(ar1 + 8*64 + lq*16);
            #pragma unroll
            for (int j=0;j<4;++j){
                acc[0][j] = __builtin_amdgcn_mfma_i32_16x16x64_i8(a0, bA[j], acc[0][j], 0,0,0);
                acc[1][j] = __builtin_amdgcn_mfma_i32_16x16x64_i8(a1, bA[j], acc[1][j], 0,0,0);
            }
        }
        if (DUAL) {   // += W(i,f) * hsave, tiles 0..7 (single-buffered; t=0 only)
            const unsigned char* hr0 = &hsave[l15][0];
            const unsigned char* hr1 = &hsave[16+l15][0];
            #pragma unroll 1
            for (int kt=0; kt<8; ++kt){
                const unsigned char* p = bp0 + kt*8192;
                #pragma unroll
                for (int j=0;j<4;++j) bA[j] = *(const int4v*)(p + j*1024);
                int4v a0 = *(const int4v*)(hr0 + kt*64 + lq*16);
                int4v a1 = *(const int4v*)(hr1 + kt*64 + lq*16);
                #pragma unroll
                for (int j=0;j<4;++j){
                    acc[0][j] = __builtin_amdgcn_mfma_i32_16x16x64_i8(a0, bA[j], acc[0][j], 0,0,0);
                    acc[1][j] = __builtin_amdgcn_mfma_i32_16x16x64_i8(a1, bA[j], acc[1][j], 0,0,0);
                }
            }
        }
        // epilogue half0: j 0,1 = i-gate (up=j&1); j 2,3 = f-gate
        #pragma unroll
        for (int mf=0;mf<2;++mf)
            #pragma unroll
            for (int up=0;up<2;++up)
                #pragma unroll
                for (int r=0;r<4;++r){
                    int idx = (mf*2+up)*4 + r;
                    sI[idx] = rcpf_(1.f+ex2(nK1*(float)acc[mf][0+up][r]));
                    cc[idx] = rcpf_(1.f+ex2(nK1*(float)acc[mf][2+up][r])) * cc[idx];
                }
        // ================= half 1: g,o ================= (bB holds tile0)
        #pragma unroll
        for (int mf=0;mf<2;++mf)
            #pragma unroll
            for (int j=0;j<4;++j) acc[mf][j] = (int4v){0,0,0,0};
        #pragma unroll 1
        for (int kt=0; kt<8; kt+=2){
            const unsigned char* p1 = bp1 + (kt+1)*8192;
            #pragma unroll
            for (int j=0;j<4;++j) bA[j] = *(const int4v*)(p1 + j*1024);
            int4v a0 = *(const int4v*)(ar0 + kt*64 + lq*16);
            int4v a1 = *(const int4v*)(ar1 + kt*64 + lq*16);
            #pragma unroll
            for (int j=0;j<4;++j){
                acc[0][j] = __builtin_amdgcn_mfma_i32_16x16x64_i8(a0, bB[j], acc[0][j], 0,0,0);
                acc[1][j] = __builtin_amdgcn_mfma_i32_16x16x64_i8(a1, bB[j], acc[1][j], 0,0,0);
            }
            const unsigned char* p2 = bp1 + (kt+2)*8192;
            #pragma unroll
            for (int j=0;j<4;++j) bB[j] = *(const int4v*)(p2 + j*1024);
            a0 = *(const int4v*)(ar0 + (kt+1)*64 + lq*16);
            a1 = *(const int4v*)(ar1 + (kt+1)*64 + lq*16);
            #pragma unroll
            for (int j=0;j<4;++j){
                acc[0][j] = __builtin_amdgcn_mfma_i32_16x16x64_i8(a0, bA[j], acc[0][j], 0,0,0);
                acc[1][j] = __builtin_amdgcn_mfma_i32_16x16x64_i8(a1, bA[j], acc[1][j], 0,0,0);
            }
        }
        {   // kt=8 tail: ALL accs use bB (tile 8 after swap-trace)
            int4v a0 = *(const int4v*)(ar0 + 8*64 + lq*16);
            int4v a1 = *(const int4v*)(ar1 + 8*64 + lq*16);
            #pragma unroll
            for (int j=0;j<4;++j){
                acc[0][j] = __builtin_amdgcn_mfma_i32_16x16x64_i8(a0, bB[j], acc[0][j], 0,0,0);
                acc[1][j] = __builtin_amdgcn_mfma_i32_16x16x64_i8(a1, bB[j], acc[1][j], 0,0,0);
            }
        }
        if (DUAL) {   // += W(g,o) * hsave, tiles 0..7
            const unsigned char* hr0 = &hsave[l15][0];
            const unsigned char* hr1 = &hsave[16+l15][0];
            #pragma unroll 1
            for (int kt=0; kt<8; ++kt){
                const unsigned char* p = bp1 + kt*8192;
                #pragma unroll
                for (int j=0;j<4;++j) bA[j] = *(const int4v*)(p + j*1024);
                int4v a0 = *(const int4v*)(hr0 + kt*64 + lq*16);
                int4v a1 = *(const int4v*)(hr1 + kt*64 + lq*16);
                #pragma unroll
                for (int j=0;j<4;++j){
                    acc[0][j] = __builtin_amdgcn_mfma_i32_16x16x64_i8(a0, bA[j], acc[0][j], 0,0,0);
                    acc[1][j] = __builtin_amdgcn_mfma_i32_16x16x64_i8(a1, bA[j], acc[1][j], 0,0,0);
                }
            }
        }
        // epilogue half1: j 0,1 = g-gate; j 2,3 = o-gate
        #pragma unroll
        for (int mf=0;mf<2;++mf)
            #pragma unroll
            for (int up=0;up<2;++up)
                #pragma unroll
                for (int r=0;r<4;++r){
                    int idx = (mf*2+up)*4 + r;
                    float tg = 2.f*rcpf_(1.f+ex2(nK2*(float)acc[mf][0+up][r])) - 1.f;
                    float so = rcpf_(1.f+ex2(nK1*(float)acc[mf][2+up][r]));
                    float cn = cc[idx] + sI[idx]*tg;
                    cc[idx] = cn;
                    float h = so*tanh_(cn);
                    int q = (int)rintf(h*127.f);
                    if (DEFER) hq[idx] = q;
                    else abuf[wbuf][mf*16+lq*4+r][ch*32+up*16+l15] = (unsigned char)q;
                }
    };

    const unsigned char* wsp = wpack;
    const unsigned char* wpp = wpack + (size_t)LSTR;
    const unsigned char* wdp = wpack + 2*(size_t)LSTR;
    int dmy[16];

    // ---- speed encoder ----
    {
        const float nK1 = -gs0*LOG2E, nK2 = -2.f*gs0*LOG2E;
        #pragma unroll 1
        for (int t=0;t<16;++t){
            int rb=t&1, wbuf=(t+1)&1;
            if (t<15 && tid<128){
                int m=tid>>2, f3=tid&3;
                float x = speed[((size_t)(row0+m)*16 + t+1)*4 + f3];
                int q = (int)rintf(fminf(fmaxf(x*31.75f,-127.f),127.f));
                unsigned char qb=(unsigned char)q;
                abuf[wbuf][m][512+f3]=qb; abuf[wbuf][m][516+f3]=qb; abuf[wbuf][m][520+f3]=qb; abuf[wbuf][m][524+f3]=qb;
            }
            pass(rb,wbuf,wsp,nK1,nK2,0,0,dmy);
            __syncthreads();
        }
    }
    // ---- speed -> pos transition (final h_s in abuf[0]) ----
    for (int i=tid; i<MTILE*32; i+=NTHR){
        int m=i>>5, cb=(i&31)*16;
        *(int4v*)&hsave[m][cb] = *(const int4v*)&abuf[0][m][cb];
        *(int4v*)&abuf[0][m][cb] = (int4v){0,0,0,0};
    }
    #pragma unroll
    for (int mf=0;mf<2;++mf)
        #pragma unroll
        for (int up=0;up<2;++up)
            #pragma unroll
            for (int r=0;r<4;++r){
                int idx=(mf*2+up)*4+r;
                csave[mf*16+lq*4+r][ch*32+up*16+l15] = cc[idx];
            }
    #pragma unroll
    for (int i=0;i<16;++i) cc[i]=0.f;
    if (tid < 128) {
        int m = tid>>2, f3 = tid&3;
        float x = pos[((size_t)(row0+m)*16 + 0)*4 + f3];
        int q = (int)rintf(fminf(fmaxf(x*31.75f,-127.f),127.f));
        unsigned char qb = (unsigned char)q;
        abuf[0][m][512+f3]=qb; abuf[0][m][516+f3]=qb; abuf[0][m][520+f3]=qb; abuf[0][m][524+f3]=qb;
    }
    __syncthreads();

    // ---- pos encoder ----
    {
        const float nK1 = -gs1*LOG2E, nK2 = -2.f*gs1*LOG2E;
        #pragma unroll 1
        for (int t=0;t<16;++t){
            int rb=t&1, wbuf=(t+1)&1;
            if (t<15 && tid<128){
                int m=tid>>2, f3=tid&3;
                float x = pos[((size_t)(row0+m)*16 + t+1)*4 + f3];
                int q = (int)rintf(fminf(fmaxf(x*31.75f,-127.f),127.f));
                unsigned char qb=(unsigned char)q;
                abuf[wbuf][m][512+f3]=qb; abuf[wbuf][m][516+f3]=qb; abuf[wbuf][m][520+f3]=qb; abuf[wbuf][m][524+f3]=qb;
            }
            pass(rb,wbuf,wpp,nK1,nK2,0,0,dmy);
            __syncthreads();
        }
    }
    // ---- combine: c += c_s; x=pos[:,15,:]; h_p in abuf[0], h_s in hsave ----
    if (tid < 128) {
        int m = tid>>2, f3 = tid&3;
        float x = pos[((size_t)(row0+m)*16 + 15)*4 + f3];
        int q = (int)rintf(fminf(fmaxf(x*31.75f,-127.f),127.f));
        unsigned char qb = (unsigned char)q;
        abuf[0][m][512+f3]=qb; abuf[0][m][516+f3]=qb; abuf[0][m][520+f3]=qb; abuf[0][m][524+f3]=qb;
    }
    #pragma unroll
    for (int mf=0;mf<2;++mf)
        #pragma unroll
        for (int up=0;up<2;++up)
            #pragma unroll
            for (int r=0;r<4;++r){
                int idx=(mf*2+up)*4+r;
                cc[idx] += csave[mf*16+lq*4+r][ch*32+up*16+l15];
            }
    __syncthreads();

    // ---- decoder ----
    {
        const float nK1 = -gs2*LOG2E, nK2 = -2.f*gs2*LOG2E;
        #pragma unroll 1
        for (int t=0;t<16;++t){
            int hb;
            if (t == 0) {
                int hq[16];
                pass(0,0,wdp,nK1,nK2,1,1,hq);
                __syncthreads();
                #pragma unroll
                for (int mf=0;mf<2;++mf)
                    #pragma unroll
                    for (int up=0;up<2;++up)
                        #pragma unroll
                        for (int r=0;r<4;++r){
                            int idx=(mf*2+up)*4+r;
                            abuf[0][mf*16+lq*4+r][ch*32+up*16+l15] = (unsigned char)hq[idx];
                        }
                hb = 0;
            } else {
                int rb=(t+1)&1, wbuf=t&1;
                pass(rb,wbuf,wdp,nK1,nK2,0,0,dmy);
                hb = wbuf;
            }
            __syncthreads();
            {   // crossing partials: wave wv covers k-slice [wv*32, wv*32+32)
                int r = lane>>1, col = lane&1;
                const unsigned char* hp = &abuf[hb][r][wv*32];
                const float* wp = &smallw[col*512 + wv*32];
                float p = 0.f;
                #pragma unroll
                for (int k4=0;k4<8;++k4){
                    int v = *(const int*)(hp + k4*4);
                    p += (float)((signed char)(v    )) * wp[k4*4+0];
                    p += (float)((signed char)(v>>8 )) * wp[k4*4+1];
                    p += (float)((signed char)(v>>16)) * wp[k4*4+2];
                    p += (float)((signed char)(v>>24)) * wp[k4*4+3];
                }
                partial[wv*64 + lane] = p;
            }
            __syncthreads();
            if (wv == 0) {
                float p = 0.f;
                #pragma unroll
                for (int i=0;i<16;++i) p += partial[i*64 + lane];
                int r = lane>>1, col = lane&1;
                p = p*(1.f/127.f) + smallw[1024+col];
                float cr = fmaxf(p, 0.f);
                float other = __shfl_xor(cr, 1, 64);
                float mx = fmaxf(cr, other);
                float e0 = ex2(LOG2E*(cr-mx)), e1 = ex2(LOG2E*(other-mx));
                out[((size_t)(row0+r))*32 + t*2 + col] = e0*rcpn(e0+e1);
                float c0v = col ? other : cr;
                float c1v = col ? cr : other;
                #pragma unroll
                for (int q2=0;q2<2;++q2){
                    int e = col*2 + q2;
                    float lp = fmaxf(c0v*smallw[1026+e*2] + c1v*smallw[1026+e*2+1] + smallw[1034+e], 0.f);
                    int qv = (int)rintf(fminf(lp*31.75f, 127.f));
                    unsigned char qb = (unsigned char)qv;
                    abuf[hb][r][512+e]=qb; abuf[hb][r][516+e]=qb; abuf[hb][r][520+e]=qb; abuf[hb][r][524+e]=qb;
                }
            }
            __syncthreads();
        }
    }
}

extern "C" void kernel_launch(void* const* d_in, const int* in_sizes, int n_in,
                              void* d_out, int out_size, void* d_ws, size_t ws_size,
                              hipStream_t stream)
{
    (void)in_sizes; (void)n_in; (void)out_size; (void)ws_size;
    const float* speed = (const float*)d_in[0];
    const float* pos   = (const float*)d_in[1];
    const float* Ws_ih = (const float*)d_in[2];
    const float* Ws_hh = (const float*)d_in[3];
    const float* bs_ih = (const float*)d_in[4];
    const float* bs_hh = (const float*)d_in[5];
    const float* Wp_ih = (const float*)d_in[6];
    const float* Wp_hh = (const float*)d_in[7];
    const float* bp_ih = (const float*)d_in[8];
    const float* bp_hh = (const float*)d_in[9];
    const float* Wd_ih = (const float*)d_in[10];
    const float* Wd_hh = (const float*)d_in[11];
    const float* bd_ih = (const float*)d_in[12];
    const float* bd_hh = (const float*)d_in[13];
    const float* W_fc  = (const float*)d_in[14];
    const float* b_fc  = (const float*)d_in[15];
    const float* W_emb = (const float*)d_in[16];
    const float* b_emb = (const float*)d_in[17];

    unsigned char* wp8 = (unsigned char*)d_ws;
    int*   smax  = (int*)(wp8 + 3*(size_t)LSTR);
    float* gsout = (float*)(wp8 + 3*(size_t)LSTR + 16);

    scale_k<<<96, 256, 0, stream>>>(Ws_ih,Ws_hh,bs_ih,bs_hh, Wp_ih,Wp_hh,bp_ih,bp_hh,
                                    Wd_ih,Wd_hh,bd_ih,bd_hh, smax);
    int gb = (LSTR/4 + 255) / 256;
    pack_k<<<gb, 256, 0, stream>>>(Ws_ih, Ws_hh, bs_ih, bs_hh, smax, 0, wp8,                  gsout);
    pack_k<<<gb, 256, 0, stream>>>(Wp_ih, Wp_hh, bp_ih, bp_hh, smax, 1, wp8 +   (size_t)LSTR, gsout);
    pack_k<<<gb, 256, 0, stream>>>(Wd_ih, Wd_hh, bd_ih, bd_hh, smax, 2, wp8 + 2*(size_t)LSTR, gsout);
    lstm_all<<<NBLK, NTHR, 0, stream>>>(speed, pos, wp8, gsout,
                                        W_fc, b_fc, W_emb, b_emb, (float*)d_out);
}

// Round 14
// 796.730 us; speedup vs baseline: 1.2497x; 1.2497x over previous
//
#include <hip/hip_runtime.h>

#define NBLK 256
#define NTHR 1024                // 16 waves = 4/SIMD: TLP hides L2 latency; 128 unified regs/wave
#define MTILE 32
#define KPADI 592                // abuf row stride bytes (16-aligned)
#define HSTR  528                // hsave row stride bytes
#define CHB   (9*8*64*16)        // 73728 bytes per 16-col chunk per LSTM (9 k-tiles of K=64)
#define LSTR  (16*CHB)           // 1179648 bytes per LSTM

typedef __attribute__((ext_vector_type(4))) int int4v;

__device__ inline float ex2(float x){ return __builtin_amdgcn_exp2f(x); }
__device__ inline float rcpf_(float d){ return __builtin_amdgcn_rcpf(d); }
__device__ inline float rcpn(float d){ float r=__builtin_amdgcn_rcpf(d); return r*(2.f-d*r); }
#define LOG2E 1.4426950408889634f
__device__ inline float tanh_(float x){ return 2.f*rcpf_(1.f+ex2(-2.f*LOG2E*x))-1.f; }

// ---- per-LSTM scale: max(|Whh|, |Wih|, |bih+bhh|/2), via atomicMax on float bits.
__global__ void scale_k(const float* Ws_ih, const float* Ws_hh, const float* bs_ih, const float* bs_hh,
                        const float* Wp_ih, const float* Wp_hh, const float* bp_ih, const float* bp_hh,
                        const float* Wd_ih, const float* Wd_hh, const float* bd_ih, const float* bd_hh,
                        int* smax)
{
    int L = blockIdx.x >> 5;
    int blk = blockIdx.x & 31;
    const float* Wih = L==0 ? Ws_ih : L==1 ? Wp_ih : Wd_ih;
    const float* Whh = L==0 ? Ws_hh : L==1 ? Wp_hh : Wd_hh;
    const float* bih = L==0 ? bs_ih : L==1 ? bp_ih : bd_ih;
    const float* bhh = L==0 ? bs_hh : L==1 ? bp_hh : bd_hh;
    float m = 0.f;
    for (int i = blk*256 + threadIdx.x; i < 2048*512; i += 32*256) m = fmaxf(m, fabsf(Whh[i]));
    for (int i = blk*256 + threadIdx.x; i < 2048*4;   i += 32*256) m = fmaxf(m, fabsf(Wih[i]));
    for (int i = blk*256 + threadIdx.x; i < 2048;     i += 32*256) m = fmaxf(m, 0.5f*fabsf(bih[i]+bhh[i]));
    __shared__ float red[256];
    red[threadIdx.x] = m; __syncthreads();
    for (int s = 128; s; s >>= 1){
        if (threadIdx.x < s) red[threadIdx.x] = fmaxf(red[threadIdx.x], red[threadIdx.x+s]);
        __syncthreads();
    }
    if (threadIdx.x == 0) atomicMax(&smax[L], __float_as_int(red[0]));
}

// Pack: BP[chunk(16)][kt(9)][nt(8)][lane(64)][16 i8]; element B[k][n]:
// n=(chunk*8+nt)*16+(lane&15), k=kt*64+(lane>>4)*16+j. Packed n decode: ch=n>>7,
// g=(n>>5)&3, u=n&31 -> row=g*512+ch*32+u. K rows: 0..511=Whh; 512..527=Wih
// x-replicas (A holds x/4, 4 copies per dim); 528..529=(b_ih+b_hh)/2 (A holds 127);
// 530..575=0.  Gate order per chunk: nt 0,1=i 2,3=f 4,5=g 6,7=o (up=nt&1).
__global__ void pack_k(const float* Wih, const float* Whh, const float* bih, const float* bhh,
                       const int* smax, int L, unsigned char* dst, float* gsout)
{
    int f4 = blockIdx.x*256 + threadIdx.x;
    if (f4*4 >= LSTR) return;
    float mx = __int_as_float(smax[L]);
    float inv = 127.f / mx;
    if (blockIdx.x==0 && threadIdx.x==0) gsout[L] = mx * (1.f/(127.f*127.f));
    int fb = f4*4;
    int lane=(fb>>4)&63, nt=(fb>>10)&7, t=fb>>13;
    int kt=t%9, chunk=t/9;
    int n = (chunk*8+nt)*16 + (lane&15);
    int ch=n>>7, g=(n>>5)&3, u=n&31;
    int row = g*512 + ch*32 + u;
    int kbase = kt*64 + ((lane>>4)<<4) + (fb&15);
    unsigned out = 0;
    #pragma unroll
    for (int b=0;b<4;++b){
        int k = kbase + b;
        float v = 0.f;
        if (k < 512)      v = Whh[row*512+k];
        else if (k < 528) v = Wih[row*4 + (k&3)];
        else if (k < 530) v = 0.5f*(bih[row]+bhh[row]);
        int q = (int)rintf(v*inv);
        q = q>127?127:(q<-127?-127:q);
        out |= ((unsigned)(q & 255)) << (8*b);
    }
    *(unsigned*)(dst + fb) = out;
}

__global__ __launch_bounds__(NTHR, 1)
void lstm_all(const float* __restrict__ speed, const float* __restrict__ pos,
              const unsigned char* __restrict__ wpack, const float* __restrict__ gsb,
              const float* __restrict__ wfc, const float* __restrict__ bfc,
              const float* __restrict__ wemb, const float* __restrict__ bemb,
              float* __restrict__ out)
{
    __shared__ __align__(16) unsigned char abuf[2][MTILE][KPADI];  // 37888 B
    __shared__ __align__(16) unsigned char hsave[MTILE][HSTR];     // 16896 B
    __shared__ float csave[MTILE][512];                            // 65536 B
    __shared__ float smallw[1040];                                 // 4160 B
    __shared__ float partial[NTHR];                                // 4096 B

    const int tid  = threadIdx.x;
    const int lane = tid & 63;
    const int wv   = tid >> 6;          // 0..15; wave owns chunk (wv+cstag)&15
    const int row0 = blockIdx.x * MTILE;
    const int l15  = lane & 15;
    const int lq   = lane >> 4;
    const int cstag = blockIdx.x & 15;  // chunk stagger across blocks
    const int ch   = (wv + cstag) & 15;

    const float gs0 = gsb[0], gs1 = gsb[1], gs2 = gsb[2];

    // ---- init LDS ----
    {
        for (int i = tid; i < 2*MTILE*(KPADI/16); i += NTHR) {
            int b = i / (MTILE*(KPADI/16));
            int rmd = i % (MTILE*(KPADI/16));
            int m = rmd / (KPADI/16), c16 = (rmd % (KPADI/16))*16;
            *(int4v*)&abuf[b][m][c16] = (int4v){0,0,0,0};
        }
        for (int i = tid; i < 1024; i += NTHR) smallw[i] = wfc[i];
        if (tid < 2) smallw[1024+tid] = bfc[tid];
        if (tid < 8) smallw[1026+tid] = wemb[tid];
        if (tid < 4) smallw[1034+tid] = bemb[tid];
    }
    __syncthreads();
    if (tid < 64) { int b = tid>>5, m = tid&31; abuf[b][m][528] = 127; abuf[b][m][529] = 127; }
    if (tid < 128) {
        int m = tid>>2, f3 = tid&3;
        float x = speed[((size_t)(row0+m)*16 + 0)*4 + f3];
        int q = (int)rintf(fminf(fmaxf(x*31.75f,-127.f),127.f));
        unsigned char qb = (unsigned char)q;
        abuf[0][m][512+f3]=qb; abuf[0][m][516+f3]=qb; abuf[0][m][520+f3]=qb; abuf[0][m][524+f3]=qb;
    }
    __syncthreads();

    float cc[16];
    #pragma unroll
    for (int i = 0; i < 16; ++i) cc[i]=0.f;

    // One cell step for this wave's chunk (128 gate-cols = 32 hidden), M=32 rows.
    // Gates split: half0 = i,f (nt0-3) -> sI + c*=sig(f); half1 = g,o (nt4-7).
    // SINGLE-buffered bA[4], uniform 9-tile loop: ~108 unified regs < 128 cap;
    // load latency is hidden by 4 waves/SIMD TLP, not intra-wave pipelining.
    auto pass = [&](int rb, int wbuf, const unsigned char* wl,
                    float nK1, float nK2, int DUAL, int DEFER, int (&hq)[16]) {
        const unsigned char* bp0 = wl + (size_t)ch*CHB + lane*16;   // nt 0-3
        const unsigned char* bp1 = bp0 + 4*1024;                    // nt 4-7
        const unsigned char* ar0 = &abuf[rb][l15][0];
        const unsigned char* ar1 = &abuf[rb][16+l15][0];
        float sI[16];
        int4v bA[4], acc[2][4];
        // ================= half 0: i,f =================
        #pragma unroll
        for (int mf=0;mf<2;++mf)
            #pragma unroll
            for (int j=0;j<4;++j) acc[mf][j] = (int4v){0,0,0,0};
        #pragma unroll 1
        for (int kt=0; kt<9; ++kt){
            const unsigned char* p = bp0 + kt*8192;
            #pragma unroll
            for (int j=0;j<4;++j) bA[j] = *(const int4v*)(p + j*1024);
            int4v a0 = *(const int4v*)(ar0 + kt*64 + lq*16);
            int4v a1 = *(const int4v*)(ar1 + kt*64 + lq*16);
            #pragma unroll
            for (int j=0;j<4;++j){
                acc[0][j] = __builtin_amdgcn_mfma_i32_16x16x64_i8(a0, bA[j], acc[0][j], 0,0,0);
                acc[1][j] = __builtin_amdgcn_mfma_i32_16x16x64_i8(a1, bA[j], acc[1][j], 0,0,0);
            }
        }
        if (DUAL) {   // += W(i,f) * hsave, tiles 0..7 (t=0 only)
            const unsigned char* hr0 = &hsave[l15][0];
            const unsigned char* hr1 = &hsave[16+l15][0];
            #pragma unroll 1
            for (int kt=0; kt<8; ++kt){
                const unsigned char* p = bp0 + kt*8192;
                #pragma unroll
                for (int j=0;j<4;++j) bA[j] = *(const int4v*)(p + j*1024);
                int4v a0 = *(const int4v*)(hr0 + kt*64 + lq*16);
                int4v a1 = *(const int4v*)(hr1 + kt*64 + lq*16);
                #pragma unroll
                for (int j=0;j<4;++j){
                    acc[0][j] = __builtin_amdgcn_mfma_i32_16x16x64_i8(a0, bA[j], acc[0][j], 0,0,0);
                    acc[1][j] = __builtin_amdgcn_mfma_i32_16x16x64_i8(a1, bA[j], acc[1][j], 0,0,0);
                }
            }
        }
        // epilogue half0: j 0,1 = i-gate (up=j&1); j 2,3 = f-gate
        #pragma unroll
        for (int mf=0;mf<2;++mf)
            #pragma unroll
            for (int up=0;up<2;++up)
                #pragma unroll
                for (int r=0;r<4;++r){
                    int idx = (mf*2+up)*4 + r;
                    sI[idx] = rcpf_(1.f+ex2(nK1*(float)acc[mf][0+up][r]));
                    cc[idx] = rcpf_(1.f+ex2(nK1*(float)acc[mf][2+up][r])) * cc[idx];
                }
        // ================= half 1: g,o =================
        #pragma unroll
        for (int mf=0;mf<2;++mf)
            #pragma unroll
            for (int j=0;j<4;++j) acc[mf][j] = (int4v){0,0,0,0};
        #pragma unroll 1
        for (int kt=0; kt<9; ++kt){
            const unsigned char* p = bp1 + kt*8192;
            #pragma unroll
            for (int j=0;j<4;++j) bA[j] = *(const int4v*)(p + j*1024);
            int4v a0 = *(const int4v*)(ar0 + kt*64 + lq*16);
            int4v a1 = *(const int4v*)(ar1 + kt*64 + lq*16);
            #pragma unroll
            for (int j=0;j<4;++j){
                acc[0][j] = __builtin_amdgcn_mfma_i32_16x16x64_i8(a0, bA[j], acc[0][j], 0,0,0);
                acc[1][j] = __builtin_amdgcn_mfma_i32_16x16x64_i8(a1, bA[j], acc[1][j], 0,0,0);
            }
        }
        if (DUAL) {   // += W(g,o) * hsave, tiles 0..7
            const unsigned char* hr0 = &hsave[l15][0];
            const unsigned char* hr1 = &hsave[16+l15][0];
            #pragma unroll 1
            for (int kt=0; kt<8; ++kt){
                const unsigned char* p = bp1 + kt*8192;
                #pragma unroll
                for (int j=0;j<4;++j) bA[j] = *(const int4v*)(p + j*1024);
                int4v a0 = *(const int4v*)(hr0 + kt*64 + lq*16);
                int4v a1 = *(const int4v*)(hr1 + kt*64 + lq*16);
                #pragma unroll
                for (int j=0;j<4;++j){
                    acc[0][j] = __builtin_amdgcn_mfma_i32_16x16x64_i8(a0, bA[j], acc[0][j], 0,0,0);
                    acc[1][j] = __builtin_amdgcn_mfma_i32_16x16x64_i8(a1, bA[j], acc[1][j], 0,0,0);
                }
            }
        }
        // epilogue half1: j 0,1 = g-gate; j 2,3 = o-gate
        #pragma unroll
        for (int mf=0;mf<2;++mf)
            #pragma unroll
            for (int up=0;up<2;++up)
                #pragma unroll
                for (int r=0;r<4;++r){
                    int idx = (mf*2+up)*4 + r;
                    float tg = 2.f*rcpf_(1.f+ex2(nK2*(float)acc[mf][0+up][r])) - 1.f;
                    float so = rcpf_(1.f+ex2(nK1*(float)acc[mf][2+up][r]));
                    float cn = cc[idx] + sI[idx]*tg;
                    cc[idx] = cn;
                    float h = so*tanh_(cn);
                    int q = (int)rintf(h*127.f);
                    if (DEFER) hq[idx] = q;
                    else abuf[wbuf][mf*16+lq*4+r][ch*32+up*16+l15] = (unsigned char)q;
                }
    };

    const unsigned char* wsp = wpack;
    const unsigned char* wpp = wpack + (size_t)LSTR;
    const unsigned char* wdp = wpack + 2*(size_t)LSTR;
    int dmy[16];

    // ---- speed encoder ----
    {
        const float nK1 = -gs0*LOG2E, nK2 = -2.f*gs0*LOG2E;
        #pragma unroll 1
        for (int t=0;t<16;++t){
            int rb=t&1, wbuf=(t+1)&1;
            if (t<15 && tid<128){
                int m=tid>>2, f3=tid&3;
                float x = speed[((size_t)(row0+m)*16 + t+1)*4 + f3];
                int q = (int)rintf(fminf(fmaxf(x*31.75f,-127.f),127.f));
                unsigned char qb=(unsigned char)q;
                abuf[wbuf][m][512+f3]=qb; abuf[wbuf][m][516+f3]=qb; abuf[wbuf][m][520+f3]=qb; abuf[wbuf][m][524+f3]=qb;
            }
            pass(rb,wbuf,wsp,nK1,nK2,0,0,dmy);
            __syncthreads();
        }
    }
    // ---- speed -> pos transition (final h_s in abuf[0]) ----
    for (int i=tid; i<MTILE*32; i+=NTHR){
        int m=i>>5, cb=(i&31)*16;
        *(int4v*)&hsave[m][cb] = *(const int4v*)&abuf[0][m][cb];
        *(int4v*)&abuf[0][m][cb] = (int4v){0,0,0,0};
    }
    #pragma unroll
    for (int mf=0;mf<2;++mf)
        #pragma unroll
        for (int up=0;up<2;++up)
            #pragma unroll
            for (int r=0;r<4;++r){
                int idx=(mf*2+up)*4+r;
                csave[mf*16+lq*4+r][ch*32+up*16+l15] = cc[idx];
            }
    #pragma unroll
    for (int i=0;i<16;++i) cc[i]=0.f;
    if (tid < 128) {
        int m = tid>>2, f3 = tid&3;
        float x = pos[((size_t)(row0+m)*16 + 0)*4 + f3];
        int q = (int)rintf(fminf(fmaxf(x*31.75f,-127.f),127.f));
        unsigned char qb = (unsigned char)q;
        abuf[0][m][512+f3]=qb; abuf[0][m][516+f3]=qb; abuf[0][m][520+f3]=qb; abuf[0][m][524+f3]=qb;
    }
    __syncthreads();

    // ---- pos encoder ----
    {
        const float nK1 = -gs1*LOG2E, nK2 = -2.f*gs1*LOG2E;
        #pragma unroll 1
        for (int t=0;t<16;++t){
            int rb=t&1, wbuf=(t+1)&1;
            if (t<15 && tid<128){
                int m=tid>>2, f3=tid&3;
                float x = pos[((size_t)(row0+m)*16 + t+1)*4 + f3];
                int q = (int)rintf(fminf(fmaxf(x*31.75f,-127.f),127.f));
                unsigned char qb=(unsigned char)q;
                abuf[wbuf][m][512+f3]=qb; abuf[wbuf][m][516+f3]=qb; abuf[wbuf][m][520+f3]=qb; abuf[wbuf][m][524+f3]=qb;
            }
            pass(rb,wbuf,wpp,nK1,nK2,0,0,dmy);
            __syncthreads();
        }
    }
    // ---- combine: c += c_s; x=pos[:,15,:]; h_p in abuf[0], h_s in hsave ----
    if (tid < 128) {
        int m = tid>>2, f3 = tid&3;
        float x = pos[((size_t)(row0+m)*16 + 15)*4 + f3];
        int q = (int)rintf(fminf(fmaxf(x*31.75f,-127.f),127.f));
        unsigned char qb = (unsigned char)q;
        abuf[0][m][512+f3]=qb; abuf[0][m][516+f3]=qb; abuf[0][m][520+f3]=qb; abuf[0][m][524+f3]=qb;
    }
    #pragma unroll
    for (int mf=0;mf<2;++mf)
        #pragma unroll
        for (int up=0;up<2;++up)
            #pragma unroll
            for (int r=0;r<4;++r){
                int idx=(mf*2+up)*4+r;
                cc[idx] += csave[mf*16+lq*4+r][ch*32+up*16+l15];
            }
    __syncthreads();

    // ---- decoder ----
    {
        const float nK1 = -gs2*LOG2E, nK2 = -2.f*gs2*LOG2E;
        #pragma unroll 1
        for (int t=0;t<16;++t){
            int hb;
            if (t == 0) {
                int hq[16];
                pass(0,0,wdp,nK1,nK2,1,1,hq);
                __syncthreads();
                #pragma unroll
                for (int mf=0;mf<2;++mf)
                    #pragma unroll
                    for (int up=0;up<2;++up)
                        #pragma unroll
                        for (int r=0;r<4;++r){
                            int idx=(mf*2+up)*4+r;
                            abuf[0][mf*16+lq*4+r][ch*32+up*16+l15] = (unsigned char)hq[idx];
                        }
                hb = 0;
            } else {
                int rb=(t+1)&1, wbuf=t&1;
                pass(rb,wbuf,wdp,nK1,nK2,0,0,dmy);
                hb = wbuf;
            }
            __syncthreads();
            {   // crossing partials: wave wv covers k-slice [wv*32, wv*32+32)
                int r = lane>>1, col = lane&1;
                const unsigned char* hp = &abuf[hb][r][wv*32];
                const float* wp = &smallw[col*512 + wv*32];
                float p = 0.f;
                #pragma unroll
                for (int k4=0;k4<8;++k4){
                    int v = *(const int*)(hp + k4*4);
                    p += (float)((signed char)(v    )) * wp[k4*4+0];
                    p += (float)((signed char)(v>>8 )) * wp[k4*4+1];
                    p += (float)((signed char)(v>>16)) * wp[k4*4+2];
                    p += (float)((signed char)(v>>24)) * wp[k4*4+3];
                }
                partial[wv*64 + lane] = p;
            }
            __syncthreads();
            if (wv == 0) {
                float p = 0.f;
                #pragma unroll
                for (int i=0;i<16;++i) p += partial[i*64 + lane];
                int r = lane>>1, col = lane&1;
                p = p*(1.f/127.f) + smallw[1024+col];
                float cr = fmaxf(p, 0.f);
                float other = __shfl_xor(cr, 1, 64);
                float mx = fmaxf(cr, other);
                float e0 = ex2(LOG2E*(cr-mx)), e1 = ex2(LOG2E*(other-mx));
                out[((size_t)(row0+r))*32 + t*2 + col] = e0*rcpn(e0+e1);
                float c0v = col ? other : cr;
                float c1v = col ? cr : other;
                #pragma unroll
                for (int q2=0;q2<2;++q2){
                    int e = col*2 + q2;
                    float lp = fmaxf(c0v*smallw[1026+e*2] + c1v*smallw[1026+e*2+1] + smallw[1034+e], 0.f);
                    int qv = (int)rintf(fminf(lp*31.75f, 127.f));
                    unsigned char qb = (unsigned char)qv;
                    abuf[hb][r][512+e]=qb; abuf[hb][r][516+e]=qb; abuf[hb][r][520+e]=qb; abuf[hb][r][524+e]=qb;
                }
            }
            __syncthreads();
        }
    }
}

extern "C" void kernel_launch(void* const* d_in, const int* in_sizes, int n_in,
                              void* d_out, int out_size, void* d_ws, size_t ws_size,
                              hipStream_t stream)
{
    (void)in_sizes; (void)n_in; (void)out_size; (void)ws_size;
    const float* speed = (const float*)d_in[0];
    const float* pos   = (const float*)d_in[1];
    const float* Ws_ih = (const float*)d_in[2];
    const float* Ws_hh = (const float*)d_in[3];
    const float* bs_ih = (const float*)d_in[4];
    const float* bs_hh = (const float*)d_in[5];
    const float* Wp_ih = (const float*)d_in[6];
    const float* Wp_hh = (const float*)d_in[7];
    const float* bp_ih = (const float*)d_in[8];
    const float* bp_hh = (const float*)d_in[9];
    const float* Wd_ih = (const float*)d_in[10];
    const float* Wd_hh = (const float*)d_in[11];
    const float* bd_ih = (const float*)d_in[12];
    const float* bd_hh = (const float*)d_in[13];
    const float* W_fc  = (const float*)d_in[14];
    const float* b_fc  = (const float*)d_in[15];
    const float* W_emb = (const float*)d_in[16];
    const float* b_emb = (const float*)d_in[17];

    unsigned char* wp8 = (unsigned char*)d_ws;
    int*   smax  = (int*)(wp8 + 3*(size_t)LSTR);
    float* gsout = (float*)(wp8 + 3*(size_t)LSTR + 16);

    scale_k<<<96, 256, 0, stream>>>(Ws_ih,Ws_hh,bs_ih,bs_hh, Wp_ih,Wp_hh,bp_ih,bp_hh,
                                    Wd_ih,Wd_hh,bd_ih,bd_hh, smax);
    int gb = (LSTR/4 + 255) / 256;
    pack_k<<<gb, 256, 0, stream>>>(Ws_ih, Ws_hh, bs_ih, bs_hh, smax, 0, wp8,                  gsout);
    pack_k<<<gb, 256, 0, stream>>>(Wp_ih, Wp_hh, bp_ih, bp_hh, smax, 1, wp8 +   (size_t)LSTR, gsout);
    pack_k<<<gb, 256, 0, stream>>>(Wd_ih, Wd_hh, bd_ih, bd_hh, smax, 2, wp8 + 2*(size_t)LSTR, gsout);
    lstm_all<<<NBLK, NTHR, 0, stream>>>(speed, pos, wp8, gsout,
                                        W_fc, b_fc, W_emb, b_emb, (float*)d_out);
}

// Round 16
// 783.647 us; speedup vs baseline: 1.2706x; 1.0167x over previous
//
#include <hip/hip_runtime.h>

#define NBLK 256
#define NTHR 1024                // 16 waves = 4/SIMD; 128 unified regs/wave
#define MTILE 32
#define KPADI 592                // abuf row stride bytes (16-aligned)
#define HSTR  528                // hsave row stride bytes
#define CHB   (9*8*64*16)        // 73728 bytes per 16-col chunk per LSTM (9 k-tiles of K=64)
#define LSTR  (16*CHB)           // 1179648 bytes per LSTM

typedef __attribute__((ext_vector_type(4))) int int4v;

__device__ inline float ex2(float x){ return __builtin_amdgcn_exp2f(x); }
__device__ inline float rcpf_(float d){ return __builtin_amdgcn_rcpf(d); }
__device__ inline float rcpn(float d){ float r=__builtin_amdgcn_rcpf(d); return r*(2.f-d*r); }
#define LOG2E 1.4426950408889634f
__device__ inline float tanh_(float x){ return 2.f*rcpf_(1.f+ex2(-2.f*LOG2E*x))-1.f; }

// ---- per-LSTM scale: max(|Whh|, |Wih|, |bih+bhh|/2), via atomicMax on float bits.
__global__ void scale_k(const float* Ws_ih, const float* Ws_hh, const float* bs_ih, const float* bs_hh,
                        const float* Wp_ih, const float* Wp_hh, const float* bp_ih, const float* bp_hh,
                        const float* Wd_ih, const float* Wd_hh, const float* bd_ih, const float* bd_hh,
                        int* smax)
{
    int L = blockIdx.x >> 5;
    int blk = blockIdx.x & 31;
    const float* Wih = L==0 ? Ws_ih : L==1 ? Wp_ih : Wd_ih;
    const float* Whh = L==0 ? Ws_hh : L==1 ? Wp_hh : Wd_hh;
    const float* bih = L==0 ? bs_ih : L==1 ? bp_ih : bd_ih;
    const float* bhh = L==0 ? bs_hh : L==1 ? bp_hh : bd_hh;
    float m = 0.f;
    for (int i = blk*256 + threadIdx.x; i < 2048*512; i += 32*256) m = fmaxf(m, fabsf(Whh[i]));
    for (int i = blk*256 + threadIdx.x; i < 2048*4;   i += 32*256) m = fmaxf(m, fabsf(Wih[i]));
    for (int i = blk*256 + threadIdx.x; i < 2048;     i += 32*256) m = fmaxf(m, 0.5f*fabsf(bih[i]+bhh[i]));
    __shared__ float red[256];
    red[threadIdx.x] = m; __syncthreads();
    for (int s = 128; s; s >>= 1){
        if (threadIdx.x < s) red[threadIdx.x] = fmaxf(red[threadIdx.x], red[threadIdx.x+s]);
        __syncthreads();
    }
    if (threadIdx.x == 0) atomicMax(&smax[L], __float_as_int(red[0]));
}

// Pack: BP[chunk(16)][kt(9)][nt(8)][lane(64)][16 i8]; element B[k][n]:
// n=(chunk*8+nt)*16+(lane&15), k=kt*64+(lane>>4)*16+j. Packed n decode: ch=n>>7,
// g=(n>>5)&3, u=n&31 -> row=g*512+ch*32+u. K rows: 0..511=Whh; 512..527=Wih
// x-replicas (A holds x/4, 4 copies per dim); 528..529=(b_ih+b_hh)/2 (A holds 127);
// 530..575=0.  Gate order per chunk: nt 0,1=i 2,3=f 4,5=g 6,7=o (up=nt&1).
__global__ void pack_k(const float* Wih, const float* Whh, const float* bih, const float* bhh,
                       const int* smax, int L, unsigned char* dst, float* gsout)
{
    int f4 = blockIdx.x*256 + threadIdx.x;
    if (f4*4 >= LSTR) return;
    float mx = __int_as_float(smax[L]);
    float inv = 127.f / mx;
    if (blockIdx.x==0 && threadIdx.x==0) gsout[L] = mx * (1.f/(127.f*127.f));
    int fb = f4*4;
    int lane=(fb>>4)&63, nt=(fb>>10)&7, t=fb>>13;
    int kt=t%9, chunk=t/9;
    int n = (chunk*8+nt)*16 + (lane&15);
    int ch=n>>7, g=(n>>5)&3, u=n&31;
    int row = g*512 + ch*32 + u;
    int kbase = kt*64 + ((lane>>4)<<4) + (fb&15);
    unsigned out = 0;
    #pragma unroll
    for (int b=0;b<4;++b){
        int k = kbase + b;
        float v = 0.f;
        if (k < 512)      v = Whh[row*512+k];
        else if (k < 528) v = Wih[row*4 + (k&3)];
        else if (k < 530) v = 0.5f*(bih[row]+bhh[row]);
        int q = (int)rintf(v*inv);
        q = q>127?127:(q<-127?-127:q);
        out |= ((unsigned)(q & 255)) << (8*b);
    }
    *(unsigned*)(dst + fb) = out;
}

__global__ __launch_bounds__(NTHR, 1)
void lstm_all(const float* __restrict__ speed, const float* __restrict__ pos,
              const unsigned char* __restrict__ wpack, const float* __restrict__ gsb,
              const float* __restrict__ wfc, const float* __restrict__ bfc,
              const float* __restrict__ wemb, const float* __restrict__ bemb,
              float* __restrict__ out)
{
    __shared__ __align__(16) unsigned char abuf[2][MTILE][KPADI];  // 37888 B
    __shared__ __align__(16) unsigned char hsave[MTILE][HSTR];     // 16896 B
    __shared__ float csave[MTILE][512];                            // 65536 B
    __shared__ float smallw[1040];                                 // 4160 B
    __shared__ float partial[NTHR];                                // 4096 B

    const int tid  = threadIdx.x;
    const int lane = tid & 63;
    const int wv   = tid >> 6;          // 0..15; wave owns chunk (wv+cstag)&15
    const int row0 = blockIdx.x * MTILE;
    const int l15  = lane & 15;
    const int lq   = lane >> 4;
    const int cstag = blockIdx.x & 15;  // chunk stagger across blocks
    const int ch   = (wv + cstag) & 15;

    const float gs0 = gsb[0], gs1 = gsb[1], gs2 = gsb[2];

    // ---- init LDS ----
    {
        for (int i = tid; i < 2*MTILE*(KPADI/16); i += NTHR) {
            int b = i / (MTILE*(KPADI/16));
            int rmd = i % (MTILE*(KPADI/16));
            int m = rmd / (KPADI/16), c16 = (rmd % (KPADI/16))*16;
            *(int4v*)&abuf[b][m][c16] = (int4v){0,0,0,0};
        }
        for (int i = tid; i < 1024; i += NTHR) smallw[i] = wfc[i];
        if (tid < 2) smallw[1024+tid] = bfc[tid];
        if (tid < 8) smallw[1026+tid] = wemb[tid];
        if (tid < 4) smallw[1034+tid] = bemb[tid];
    }
    __syncthreads();
    if (tid < 64) { int b = tid>>5, m = tid&31; abuf[b][m][528] = 127; abuf[b][m][529] = 127; }
    if (tid < 128) {
        int m = tid>>2, f3 = tid&3;
        float x = speed[((size_t)(row0+m)*16 + 0)*4 + f3];
        int q = (int)rintf(fminf(fmaxf(x*31.75f,-127.f),127.f));
        unsigned char qb = (unsigned char)q;
        abuf[0][m][512+f3]=qb; abuf[0][m][516+f3]=qb; abuf[0][m][520+f3]=qb; abuf[0][m][524+f3]=qb;
    }
    __syncthreads();

    float cc[16];
    #pragma unroll
    for (int i = 0; i < 16; ++i) cc[i]=0.f;

    // One cell step for this wave's chunk (128 gate-cols = 32 hidden), M=32 rows.
    // FULL-gates pass: acc[2][8] (64 AGPR), bA[4] loaded in two nt-groups per kt
    // -> one A-pair read per kt (9/chunk, half of R14), single unified epilogue,
    // no cross-half sI. ~124 unified regs <= 128 cap at 4 waves/SIMD.
    auto pass = [&](int rb, int wbuf, const unsigned char* wl,
                    float nK1, float nK2, int DUAL, int DEFER, int (&hq)[16]) {
        const unsigned char* bp  = wl + (size_t)ch*CHB + lane*16;
        const unsigned char* ar0 = &abuf[rb][l15][0];
        const unsigned char* ar1 = &abuf[rb][16+l15][0];
        int4v bA[4], acc[2][8];
        #pragma unroll
        for (int mf=0;mf<2;++mf)
            #pragma unroll
            for (int nt=0;nt<8;++nt) acc[mf][nt] = (int4v){0,0,0,0};
        #pragma unroll 1
        for (int kt=0; kt<9; ++kt){
            const unsigned char* p = bp + kt*8192;
            int4v a0 = *(const int4v*)(ar0 + kt*64 + lq*16);
            int4v a1 = *(const int4v*)(ar1 + kt*64 + lq*16);
            #pragma unroll
            for (int g=0; g<2; ++g){
                #pragma unroll
                for (int j=0;j<4;++j) bA[j] = *(const int4v*)(p + g*4096 + j*1024);
                #pragma unroll
                for (int j=0;j<4;++j){
                    acc[0][g*4+j] = __builtin_amdgcn_mfma_i32_16x16x64_i8(a0, bA[j], acc[0][g*4+j], 0,0,0);
                    acc[1][g*4+j] = __builtin_amdgcn_mfma_i32_16x16x64_i8(a1, bA[j], acc[1][g*4+j], 0,0,0);
                }
            }
        }
        if (DUAL) {   // += W * hsave, tiles 0..7 (decoder t=0 only)
            const unsigned char* hr0 = &hsave[l15][0];
            const unsigned char* hr1 = &hsave[16+l15][0];
            #pragma unroll 1
            for (int kt=0; kt<8; ++kt){
                const unsigned char* p = bp + kt*8192;
                int4v a0 = *(const int4v*)(hr0 + kt*64 + lq*16);
                int4v a1 = *(const int4v*)(hr1 + kt*64 + lq*16);
                #pragma unroll
                for (int g=0; g<2; ++g){
                    #pragma unroll
                    for (int j=0;j<4;++j) bA[j] = *(const int4v*)(p + g*4096 + j*1024);
                    #pragma unroll
                    for (int j=0;j<4;++j){
                        acc[0][g*4+j] = __builtin_amdgcn_mfma_i32_16x16x64_i8(a0, bA[j], acc[0][g*4+j], 0,0,0);
                        acc[1][g*4+j] = __builtin_amdgcn_mfma_i32_16x16x64_i8(a1, bA[j], acc[1][g*4+j], 0,0,0);
                    }
                }
            }
        }
        // epilogue: nt 0,1=i 2,3=f 4,5=g 6,7=o (up=nt&1) — R10-verified mapping
        #pragma unroll
        for (int mf=0;mf<2;++mf)
            #pragma unroll
            for (int up=0;up<2;++up)
                #pragma unroll
                for (int r=0;r<4;++r){
                    int idx = (mf*2+up)*4 + r;
                    float si = rcpf_(1.f+ex2(nK1*(float)acc[mf][0+up][r]));
                    float sf = rcpf_(1.f+ex2(nK1*(float)acc[mf][2+up][r]));
                    float tg = 2.f*rcpf_(1.f+ex2(nK2*(float)acc[mf][4+up][r])) - 1.f;
                    float so = rcpf_(1.f+ex2(nK1*(float)acc[mf][6+up][r]));
                    float cn = sf*cc[idx] + si*tg;
                    cc[idx] = cn;
                    float h = so*tanh_(cn);
                    int q = (int)rintf(h*127.f);
                    if (DEFER) hq[idx] = q;
                    else abuf[wbuf][mf*16+lq*4+r][ch*32+up*16+l15] = (unsigned char)q;
                }
    };

    const unsigned char* wsp = wpack;
    const unsigned char* wpp = wpack + (size_t)LSTR;
    const unsigned char* wdp = wpack + 2*(size_t)LSTR;
    int dmy[16];

    // ---- speed encoder ----
    {
        const float nK1 = -gs0*LOG2E, nK2 = -2.f*gs0*LOG2E;
        #pragma unroll 1
        for (int t=0;t<16;++t){
            int rb=t&1, wbuf=(t+1)&1;
            if (t<15 && tid<128){
                int m=tid>>2, f3=tid&3;
                float x = speed[((size_t)(row0+m)*16 + t+1)*4 + f3];
                int q = (int)rintf(fminf(fmaxf(x*31.75f,-127.f),127.f));
                unsigned char qb=(unsigned char)q;
                abuf[wbuf][m][512+f3]=qb; abuf[wbuf][m][516+f3]=qb; abuf[wbuf][m][520+f3]=qb; abuf[wbuf][m][524+f3]=qb;
            }
            pass(rb,wbuf,wsp,nK1,nK2,0,0,dmy);
            __syncthreads();
        }
    }
    // ---- speed -> pos transition (final h_s in abuf[0]) ----
    for (int i=tid; i<MTILE*32; i+=NTHR){
        int m=i>>5, cb=(i&31)*16;
        *(int4v*)&hsave[m][cb] = *(const int4v*)&abuf[0][m][cb];
        *(int4v*)&abuf[0][m][cb] = (int4v){0,0,0,0};
    }
    #pragma unroll
    for (int mf=0;mf<2;++mf)
        #pragma unroll
        for (int up=0;up<2;++up)
            #pragma unroll
            for (int r=0;r<4;++r){
                int idx=(mf*2+up)*4+r;
                csave[mf*16+lq*4+r][ch*32+up*16+l15] = cc[idx];
            }
    #pragma unroll
    for (int i=0;i<16;++i) cc[i]=0.f;
    if (tid < 128) {
        int m = tid>>2, f3 = tid&3;
        float x = pos[((size_t)(row0+m)*16 + 0)*4 + f3];
        int q = (int)rintf(fminf(fmaxf(x*31.75f,-127.f),127.f));
        unsigned char qb = (unsigned char)q;
        abuf[0][m][512+f3]=qb; abuf[0][m][516+f3]=qb; abuf[0][m][520+f3]=qb; abuf[0][m][524+f3]=qb;
    }
    __syncthreads();

    // ---- pos encoder ----
    {
        const float nK1 = -gs1*LOG2E, nK2 = -2.f*gs1*LOG2E;
        #pragma unroll 1
        for (int t=0;t<16;++t){
            int rb=t&1, wbuf=(t+1)&1;
            if (t<15 && tid<128){
                int m=tid>>2, f3=tid&3;
                float x = pos[((size_t)(row0+m)*16 + t+1)*4 + f3];
                int q = (int)rintf(fminf(fmaxf(x*31.75f,-127.f),127.f));
                unsigned char qb=(unsigned char)q;
                abuf[wbuf][m][512+f3]=qb; abuf[wbuf][m][516+f3]=qb; abuf[wbuf][m][520+f3]=qb; abuf[wbuf][m][524+f3]=qb;
            }
            pass(rb,wbuf,wpp,nK1,nK2,0,0,dmy);
            __syncthreads();
        }
    }
    // ---- combine: c += c_s; x=pos[:,15,:]; h_p in abuf[0], h_s in hsave ----
    if (tid < 128) {
        int m = tid>>2, f3 = tid&3;
        float x = pos[((size_t)(row0+m)*16 + 15)*4 + f3];
        int q = (int)rintf(fminf(fmaxf(x*31.75f,-127.f),127.f));
        unsigned char qb = (unsigned char)q;
        abuf[0][m][512+f3]=qb; abuf[0][m][516+f3]=qb; abuf[0][m][520+f3]=qb; abuf[0][m][524+f3]=qb;
    }
    #pragma unroll
    for (int mf=0;mf<2;++mf)
        #pragma unroll
        for (int up=0;up<2;++up)
            #pragma unroll
            for (int r=0;r<4;++r){
                int idx=(mf*2+up)*4+r;
                cc[idx] += csave[mf*16+lq*4+r][ch*32+up*16+l15];
            }
    __syncthreads();

    // ---- decoder ----
    {
        const float nK1 = -gs2*LOG2E, nK2 = -2.f*gs2*LOG2E;
        #pragma unroll 1
        for (int t=0;t<16;++t){
            int hb;
            if (t == 0) {
                int hq[16];
                pass(0,0,wdp,nK1,nK2,1,1,hq);
                __syncthreads();
                #pragma unroll
                for (int mf=0;mf<2;++mf)
                    #pragma unroll
                    for (int up=0;up<2;++up)
                        #pragma unroll
                        for (int r=0;r<4;++r){
                            int idx=(mf*2+up)*4+r;
                            abuf[0][mf*16+lq*4+r][ch*32+up*16+l15] = (unsigned char)hq[idx];
                        }
                hb = 0;
            } else {
                int rb=(t+1)&1, wbuf=t&1;
                pass(rb,wbuf,wdp,nK1,nK2,0,0,dmy);
                hb = wbuf;
            }
            __syncthreads();
            {   // crossing partials: wave wv covers k-slice [wv*32, wv*32+32)
                int r = lane>>1, col = lane&1;
                const unsigned char* hp = &abuf[hb][r][wv*32];
                const float* wp = &smallw[col*512 + wv*32];
                float p = 0.f;
                #pragma unroll
                for (int k4=0;k4<8;++k4){
                    int v = *(const int*)(hp + k4*4);
                    p += (float)((signed char)(v    )) * wp[k4*4+0];
                    p += (float)((signed char)(v>>8 )) * wp[k4*4+1];
                    p += (float)((signed char)(v>>16)) * wp[k4*4+2];
                    p += (float)((signed char)(v>>24)) * wp[k4*4+3];
                }
                partial[wv*64 + lane] = p;
            }
            __syncthreads();
            if (wv == 0) {
                float p = 0.f;
                #pragma unroll
                for (int i=0;i<16;++i) p += partial[i*64 + lane];
                int r = lane>>1, col = lane&1;
                p = p*(1.f/127.f) + smallw[1024+col];
                float cr = fmaxf(p, 0.f);
                float other = __shfl_xor(cr, 1, 64);
                float mx = fmaxf(cr, other);
                float e0 = ex2(LOG2E*(cr-mx)), e1 = ex2(LOG2E*(other-mx));
                out[((size_t)(row0+r))*32 + t*2 + col] = e0*rcpn(e0+e1);
                float c0v = col ? other : cr;
                float c1v = col ? cr : other;
                #pragma unroll
                for (int q2=0;q2<2;++q2){
                    int e = col*2 + q2;
                    float lp = fmaxf(c0v*smallw[1026+e*2] + c1v*smallw[1026+e*2+1] + smallw[1034+e], 0.f);
                    int qv = (int)rintf(fminf(lp*31.75f, 127.f));
                    unsigned char qb = (unsigned char)qv;
                    abuf[hb][r][512+e]=qb; abuf[hb][r][516+e]=qb; abuf[hb][r][520+e]=qb; abuf[hb][r][524+e]=qb;
                }
            }
            __syncthreads();
        }
    }
}

extern "C" void kernel_launch(void* const* d_in, const int* in_sizes, int n_in,
                              void* d_out, int out_size, void* d_ws, size_t ws_size,
                              hipStream_t stream)
{
    (void)in_sizes; (void)n_in; (void)out_size; (void)ws_size;
    const float* speed = (const float*)d_in[0];
    const float* pos   = (const float*)d_in[1];
    const float* Ws_ih = (const float*)d_in[2];
    const float* Ws_hh = (const float*)d_in[3];
    const float* bs_ih = (const float*)d_in[4];
    const float* bs_hh = (const float*)d_in[5];
    const float* Wp_ih = (const float*)d_in[6];
    const float* Wp_hh = (const float*)d_in[7];
    const float* bp_ih = (const float*)d_in[8];
    const float* bp_hh = (const float*)d_in[9];
    const float* Wd_ih = (const float*)d_in[10];
    const float* Wd_hh = (const float*)d_in[11];
    const float* bd_ih = (const float*)d_in[12];
    const float* bd_hh = (const float*)d_in[13];
    const float* W_fc  = (const float*)d_in[14];
    const float* b_fc  = (const float*)d_in[15];
    const float* W_emb = (const float*)d_in[16];
    const float* b_emb = (const float*)d_in[17];

    unsigned char* wp8 = (unsigned char*)d_ws;
    int*   smax  = (int*)(wp8 + 3*(size_t)LSTR);
    float* gsout = (float*)(wp8 + 3*(size_t)LSTR + 16);

    scale_k<<<96, 256, 0, stream>>>(Ws_ih,Ws_hh,bs_ih,bs_hh, Wp_ih,Wp_hh,bp_ih,bp_hh,
                                    Wd_ih,Wd_hh,bd_ih,bd_hh, smax);
    int gb = (LSTR/4 + 255) / 256;
    pack_k<<<gb, 256, 0, stream>>>(Ws_ih, Ws_hh, bs_ih, bs_hh, smax, 0, wp8,                  gsout);
    pack_k<<<gb, 256, 0, stream>>>(Wp_ih, Wp_hh, bp_ih, bp_hh, smax, 1, wp8 +   (size_t)LSTR, gsout);
    pack_k<<<gb, 256, 0, stream>>>(Wd_ih, Wd_hh, bd_ih, bd_hh, smax, 2, wp8 + 2*(size_t)LSTR, gsout);
    lstm_all<<<NBLK, NTHR, 0, stream>>>(speed, pos, wp8, gsout,
                                        W_fc, b_fc, W_emb, b_emb, (float*)d_out);
}

// Round 17
// 726.841 us; speedup vs baseline: 1.3699x; 1.0782x over previous
//
#include <hip/hip_runtime.h>

#define NBLK 256
#define NTHR 512
#define MTILE 32
#define KPADI 592                // abuf row stride bytes (16-aligned)
#define HSTR  528                // hsave row stride bytes
#define CHB   (9*8*64*16)        // 73728 bytes per 16-col chunk per LSTM (9 k-tiles of K=64)
#define LSTR  (16*CHB)           // 1179648 bytes per LSTM

typedef __attribute__((ext_vector_type(4))) int int4v;

__device__ inline float ex2(float x){ return __builtin_amdgcn_exp2f(x); }
__device__ inline float rcpf_(float d){ return __builtin_amdgcn_rcpf(d); }
__device__ inline float rcpn(float d){ float r=__builtin_amdgcn_rcpf(d); return r*(2.f-d*r); }
#define LOG2E 1.4426950408889634f
__device__ inline float sigf(float x){ return rcpf_(1.f+ex2(-LOG2E*x)); }
__device__ inline float tanh_(float x){ return 2.f*rcpf_(1.f+ex2(-2.f*LOG2E*x))-1.f; }

// ---- per-LSTM scale: max(|Whh|, |Wih|, |bih+bhh|/2), via atomicMax on float bits.
__global__ void scale_k(const float* Ws_ih, const float* Ws_hh, const float* bs_ih, const float* bs_hh,
                        const float* Wp_ih, const float* Wp_hh, const float* bp_ih, const float* bp_hh,
                        const float* Wd_ih, const float* Wd_hh, const float* bd_ih, const float* bd_hh,
                        int* smax)
{
    int L = blockIdx.x >> 5;
    int blk = blockIdx.x & 31;
    const float* Wih = L==0 ? Ws_ih : L==1 ? Wp_ih : Wd_ih;
    const float* Whh = L==0 ? Ws_hh : L==1 ? Wp_hh : Wd_hh;
    const float* bih = L==0 ? bs_ih : L==1 ? bp_ih : bd_ih;
    const float* bhh = L==0 ? bs_hh : L==1 ? bp_hh : bd_hh;
    float m = 0.f;
    for (int i = blk*256 + threadIdx.x; i < 2048*512; i += 32*256) m = fmaxf(m, fabsf(Whh[i]));
    for (int i = blk*256 + threadIdx.x; i < 2048*4;   i += 32*256) m = fmaxf(m, fabsf(Wih[i]));
    for (int i = blk*256 + threadIdx.x; i < 2048;     i += 32*256) m = fmaxf(m, 0.5f*fabsf(bih[i]+bhh[i]));
    __shared__ float red[256];
    red[threadIdx.x] = m; __syncthreads();
    for (int s = 128; s; s >>= 1){
        if (threadIdx.x < s) red[threadIdx.x] = fmaxf(red[threadIdx.x], red[threadIdx.x+s]);
        __syncthreads();
    }
    if (threadIdx.x == 0) atomicMax(&smax[L], __float_as_int(red[0]));
}

// Pack: BP[chunk(16)][kt(9)][nt(8)][lane(64)][16 i8]; element B[k][n]:
// n=(chunk*8+nt)*16+(lane&15), k=kt*64+(lane>>4)*16+j. Packed n decode: ch=n>>7,
// g=(n>>5)&3, u=n&31 -> row=g*512+ch*32+u. K rows: 0..511=Whh; 512..527=Wih
// x-replicas (A holds x/4, 4 copies per dim); 528..529=(b_ih+b_hh)/2 (A holds 127);
// 530..575=0.
__global__ void pack_k(const float* Wih, const float* Whh, const float* bih, const float* bhh,
                       const int* smax, int L, unsigned char* dst, float* gsout)
{
    int f4 = blockIdx.x*256 + threadIdx.x;
    if (f4*4 >= LSTR) return;
    float mx = __int_as_float(smax[L]);
    float inv = 127.f / mx;
    if (blockIdx.x==0 && threadIdx.x==0) gsout[L] = mx * (1.f/(127.f*127.f));
    int fb = f4*4;
    int lane=(fb>>4)&63, nt=(fb>>10)&7, t=fb>>13;
    int kt=t%9, chunk=t/9;
    int n = (chunk*8+nt)*16 + (lane&15);
    int ch=n>>7, g=(n>>5)&3, u=n&31;
    int row = g*512 + ch*32 + u;
    int kbase = kt*64 + ((lane>>4)<<4) + (fb&15);
    unsigned out = 0;
    #pragma unroll
    for (int b=0;b<4;++b){
        int k = kbase + b;
        float v = 0.f;
        if (k < 512)      v = Whh[row*512+k];
        else if (k < 528) v = Wih[row*4 + (k&3)];
        else if (k < 530) v = 0.5f*(bih[row]+bhh[row]);
        int q = (int)rintf(v*inv);
        q = q>127?127:(q<-127?-127:q);
        out |= ((unsigned)(q & 255)) << (8*b);
    }
    *(unsigned*)(dst + fb) = out;
}

__global__ __launch_bounds__(NTHR, 1)
void lstm_all(const float* __restrict__ speed, const float* __restrict__ pos,
              const unsigned char* __restrict__ wpack, const float* __restrict__ gsb,
              const float* __restrict__ wfc, const float* __restrict__ bfc,
              const float* __restrict__ wemb, const float* __restrict__ bemb,
              float* __restrict__ out)
{
    __shared__ __align__(16) unsigned char abuf[2][MTILE][KPADI];  // 37888 B
    __shared__ __align__(16) unsigned char hsave[MTILE][HSTR];     // 16896 B
    __shared__ float csave[MTILE][512];                            // 65536 B
    __shared__ float smallw[1040];
    __shared__ float partial[NTHR];

    const int tid  = threadIdx.x;
    const int lane = tid & 63;
    const int wv   = tid >> 6;          // 0..7
    const int row0 = blockIdx.x * MTILE;
    const int l15  = lane & 15;
    const int lq   = lane >> 4;
    const int cstag = blockIdx.x & 15;  // chunk stagger across blocks

    const float gs0 = gsb[0], gs1 = gsb[1], gs2 = gsb[2];

    // ---- init LDS ----
    {
        for (int i = tid; i < 2*MTILE*(KPADI/16); i += NTHR) {
            int b = i / (MTILE*(KPADI/16));
            int rmd = i % (MTILE*(KPADI/16));
            int m = rmd / (KPADI/16), c16 = (rmd % (KPADI/16))*16;
            *(int4v*)&abuf[b][m][c16] = (int4v){0,0,0,0};
        }
        for (int i = tid; i < 1024; i += NTHR) smallw[i] = wfc[i];
        if (tid < 2) smallw[1024+tid] = bfc[tid];
        if (tid < 8) smallw[1026+tid] = wemb[tid];
        if (tid < 4) smallw[1034+tid] = bemb[tid];
    }
    __syncthreads();
    if (tid < 64) { int b = tid>>5, m = tid&31; abuf[b][m][528] = 127; abuf[b][m][529] = 127; }
    if (tid < 128) {
        int m = tid>>2, f3 = tid&3;
        float x = speed[((size_t)(row0+m)*16 + 0)*4 + f3];
        int q = (int)rintf(fminf(fmaxf(x*31.75f,-127.f),127.f));
        unsigned char qb = (unsigned char)q;
        abuf[0][m][512+f3]=qb; abuf[0][m][516+f3]=qb; abuf[0][m][520+f3]=qb; abuf[0][m][524+f3]=qb;
    }
    __syncthreads();

    float cc0[16], cc1[16];
    #pragma unroll
    for (int i = 0; i < 16; ++i) { cc0[i]=0.f; cc1[i]=0.f; }

    int4v bA[8], bB[8];   // persistent ping-pong weight-tile buffers (cross-step warm start)

    auto epi = [&](int4v (&acc)[2][8], float (&cc)[16], int chunk, int wbuf,
                   float nK1, float nK2){
        #pragma unroll
        for (int mf=0;mf<2;++mf)
            #pragma unroll
            for (int up=0;up<2;++up)
                #pragma unroll
                for (int r=0;r<4;++r){
                    int idx = (mf*2+up)*4 + r;
                    float fi = (float)acc[mf][0+up][r];
                    float ff = (float)acc[mf][2+up][r];
                    float fg = (float)acc[mf][4+up][r];
                    float fo = (float)acc[mf][6+up][r];
                    float si = rcpf_(1.f+ex2(nK1*fi));     // sig(gs*acc), gs folded
                    float sf = rcpf_(1.f+ex2(nK1*ff));
                    float so = rcpf_(1.f+ex2(nK1*fo));
                    float tg = 2.f*rcpf_(1.f+ex2(nK2*fg)) - 1.f;  // tanh(gs*acc)
                    float cn = sf*cc[idx] + si*tg;
                    cc[idx] = cn;
                    float h = so*tanh_(cn);
                    int q = (int)rintf(h*127.f);
                    abuf[wbuf][mf*16+lq*4+r][chunk*32+up*16+l15] = (unsigned char)q;
                }
    };

    // Fused step: both chunk-passes, bA/bB role-rotated so the weight stream stays
    // alive through both epilogues and across the step barrier (WARM start).
    auto step2 = [&](int rb, int wbuf, const unsigned char* wl,
                     float (&c0)[16], float (&c1)[16], float gs, int WARM, int PF){
        const int ch0 = (2*wv + 0 + cstag) & 15;
        const int ch1 = (2*wv + 1 + cstag) & 15;
        const unsigned char* bp0 = wl + (size_t)ch0*CHB + lane*16;
        const unsigned char* bp1 = wl + (size_t)ch1*CHB + lane*16;
        const unsigned char* ar0 = &abuf[rb][l15][0];
        const unsigned char* ar1 = &abuf[rb][16+l15][0];
        const float nK1 = -gs*LOG2E, nK2 = -2.f*gs*LOG2E;
        int4v acc[2][8];
        // ---- chunk 0 (starts in bA; warm from previous step's prefetch) ----
        if (!WARM){
            #pragma unroll
            for (int nt=0;nt<8;++nt) bA[nt] = *(const int4v*)(bp0 + nt*1024);
        }
        #pragma unroll
        for (int mf=0;mf<2;++mf)
            #pragma unroll
            for (int nt=0;nt<8;++nt) acc[mf][nt] = (int4v){0,0,0,0};
        #pragma unroll 1
        for (int kt=0; kt<8; kt+=2){
            const unsigned char* p1 = bp0 + (kt+1)*8192;
            #pragma unroll
            for (int nt=0;nt<8;++nt) bB[nt] = *(const int4v*)(p1 + nt*1024);
            int4v a0 = *(const int4v*)(ar0 + kt*64 + lq*16);
            int4v a1 = *(const int4v*)(ar1 + kt*64 + lq*16);
            #pragma unroll
            for (int nt=0;nt<8;++nt){
                acc[0][nt] = __builtin_amdgcn_mfma_i32_16x16x64_i8(a0, bA[nt], acc[0][nt], 0,0,0);
                acc[1][nt] = __builtin_amdgcn_mfma_i32_16x16x64_i8(a1, bA[nt], acc[1][nt], 0,0,0);
            }
            const unsigned char* p2 = bp0 + (kt+2)*8192;
            #pragma unroll
            for (int nt=0;nt<8;++nt) bA[nt] = *(const int4v*)(p2 + nt*1024);
            a0 = *(const int4v*)(ar0 + (kt+1)*64 + lq*16);
            a1 = *(const int4v*)(ar1 + (kt+1)*64 + lq*16);
            #pragma unroll
            for (int nt=0;nt<8;++nt){
                acc[0][nt] = __builtin_amdgcn_mfma_i32_16x16x64_i8(a0, bB[nt], acc[0][nt], 0,0,0);
                acc[1][nt] = __builtin_amdgcn_mfma_i32_16x16x64_i8(a1, bB[nt], acc[1][nt], 0,0,0);
            }
        }
        // bA = tile8; bB dead -> prefetch chunk1 tile0 (latency hides under epi0)
        #pragma unroll
        for (int nt=0;nt<8;++nt) bB[nt] = *(const int4v*)(bp1 + nt*1024);
        {   // kt=8 tail: ALL accs use bA (tile 8)
            int4v a0 = *(const int4v*)(ar0 + 8*64 + lq*16);
            int4v a1 = *(const int4v*)(ar1 + 8*64 + lq*16);
            #pragma unroll
            for (int nt=0;nt<8;++nt){
                acc[0][nt] = __builtin_amdgcn_mfma_i32_16x16x64_i8(a0, bA[nt], acc[0][nt], 0,0,0);
                acc[1][nt] = __builtin_amdgcn_mfma_i32_16x16x64_i8(a1, bA[nt], acc[1][nt], 0,0,0);
            }
        }
        epi(acc, c0, ch0, wbuf, nK1, nK2);
        // ---- chunk 1 (starts in bB, role-swapped) ----
        #pragma unroll
        for (int mf=0;mf<2;++mf)
            #pragma unroll
            for (int nt=0;nt<8;++nt) acc[mf][nt] = (int4v){0,0,0,0};
        #pragma unroll 1
        for (int kt=0; kt<8; kt+=2){
            const unsigned char* p1 = bp1 + (kt+1)*8192;
            #pragma unroll
            for (int nt=0;nt<8;++nt) bA[nt] = *(const int4v*)(p1 + nt*1024);
            int4v a0 = *(const int4v*)(ar0 + kt*64 + lq*16);
            int4v a1 = *(const int4v*)(ar1 + kt*64 + lq*16);
            #pragma unroll
            for (int nt=0;nt<8;++nt){
                acc[0][nt] = __builtin_amdgcn_mfma_i32_16x16x64_i8(a0, bB[nt], acc[0][nt], 0,0,0);
                acc[1][nt] = __builtin_amdgcn_mfma_i32_16x16x64_i8(a1, bB[nt], acc[1][nt], 0,0,0);
            }
            const unsigned char* p2 = bp1 + (kt+2)*8192;
            #pragma unroll
            for (int nt=0;nt<8;++nt) bB[nt] = *(const int4v*)(p2 + nt*1024);
            a0 = *(const int4v*)(ar0 + (kt+1)*64 + lq*16);
            a1 = *(const int4v*)(ar1 + (kt+1)*64 + lq*16);
            #pragma unroll
            for (int nt=0;nt<8;++nt){
                acc[0][nt] = __builtin_amdgcn_mfma_i32_16x16x64_i8(a0, bA[nt], acc[0][nt], 0,0,0);
                acc[1][nt] = __builtin_amdgcn_mfma_i32_16x16x64_i8(a1, bA[nt], acc[1][nt], 0,0,0);
            }
        }
        // bB = tile8; bA dead -> cross-step prefetch (next step, same matrix/chunk)
        if (PF){
            #pragma unroll
            for (int nt=0;nt<8;++nt) bA[nt] = *(const int4v*)(bp0 + nt*1024);
        }
        {   // kt=8 tail: ALL accs use bB (tile 8)
            int4v a0 = *(const int4v*)(ar0 + 8*64 + lq*16);
            int4v a1 = *(const int4v*)(ar1 + 8*64 + lq*16);
            #pragma unroll
            for (int nt=0;nt<8;++nt){
                acc[0][nt] = __builtin_amdgcn_mfma_i32_16x16x64_i8(a0, bB[nt], acc[0][nt], 0,0,0);
                acc[1][nt] = __builtin_amdgcn_mfma_i32_16x16x64_i8(a1, bB[nt], acc[1][nt], 0,0,0);
            }
        }
        epi(acc, c1, ch1, wbuf, nK1, nK2);
    };

    // Dual-source pass (decoder t=0 only): gates = Wd*h_p + Wd*h_s + Wih*x + b, defer h.
    auto pass_dual = [&](const unsigned char* wl, int s, float (&cc)[16], float gs, int (&hq)[16]) {
        const int chunk = (2*wv + s + cstag) & 15;
        const unsigned char* bp = wl + (size_t)chunk*CHB + lane*16;
        const unsigned char* ar0 = &abuf[0][l15][0];
        const unsigned char* ar1 = &abuf[0][16+l15][0];
        int4v acc[2][8];
        #pragma unroll
        for (int mf=0;mf<2;++mf)
            #pragma unroll
            for (int nt=0;nt<8;++nt) acc[mf][nt] = (int4v){0,0,0,0};
        #pragma unroll
        for (int nt=0;nt<8;++nt) bA[nt] = *(const int4v*)(bp + nt*1024);
        #pragma unroll 1
        for (int kt=0; kt<8; kt+=2){
            const unsigned char* p1 = bp + (kt+1)*8192;
            #pragma unroll
            for (int nt=0;nt<8;++nt) bB[nt] = *(const int4v*)(p1 + nt*1024);
            int4v a0 = *(const int4v*)(ar0 + kt*64 + lq*16);
            int4v a1 = *(const int4v*)(ar1 + kt*64 + lq*16);
            #pragma unroll
            for (int nt=0;nt<8;++nt){
                acc[0][nt] = __builtin_amdgcn_mfma_i32_16x16x64_i8(a0, bA[nt], acc[0][nt], 0,0,0);
                acc[1][nt] = __builtin_amdgcn_mfma_i32_16x16x64_i8(a1, bA[nt], acc[1][nt], 0,0,0);
            }
            const unsigned char* p2 = bp + (kt+2)*8192;
            #pragma unroll
            for (int nt=0;nt<8;++nt) bA[nt] = *(const int4v*)(p2 + nt*1024);
            a0 = *(const int4v*)(ar0 + (kt+1)*64 + lq*16);
            a1 = *(const int4v*)(ar1 + (kt+1)*64 + lq*16);
            #pragma unroll
            for (int nt=0;nt<8;++nt){
                acc[0][nt] = __builtin_amdgcn_mfma_i32_16x16x64_i8(a0, bB[nt], acc[0][nt], 0,0,0);
                acc[1][nt] = __builtin_amdgcn_mfma_i32_16x16x64_i8(a1, bB[nt], acc[1][nt], 0,0,0);
            }
        }
        {   // kt=8 tail: ALL accs use bA (tile 8)
            int4v a0 = *(const int4v*)(ar0 + 8*64 + lq*16);
            int4v a1 = *(const int4v*)(ar1 + 8*64 + lq*16);
            #pragma unroll
            for (int nt=0;nt<8;++nt){
                acc[0][nt] = __builtin_amdgcn_mfma_i32_16x16x64_i8(a0, bA[nt], acc[0][nt], 0,0,0);
                acc[1][nt] = __builtin_amdgcn_mfma_i32_16x16x64_i8(a1, bA[nt], acc[1][nt], 0,0,0);
            }
        }
        {   // += W_hh * hsave, tiles 0..7
            const unsigned char* hr0 = &hsave[l15][0];
            const unsigned char* hr1 = &hsave[16+l15][0];
            #pragma unroll
            for (int nt=0;nt<8;++nt) bA[nt] = *(const int4v*)(bp + nt*1024);
            #pragma unroll 1
            for (int kt=0; kt<8; kt+=2){
                const unsigned char* p1 = bp + (kt+1)*8192;
                #pragma unroll
                for (int nt=0;nt<8;++nt) bB[nt] = *(const int4v*)(p1 + nt*1024);
                int4v a0 = *(const int4v*)(hr0 + kt*64 + lq*16);
                int4v a1 = *(const int4v*)(hr1 + kt*64 + lq*16);
                #pragma unroll
                for (int nt=0;nt<8;++nt){
                    acc[0][nt] = __builtin_amdgcn_mfma_i32_16x16x64_i8(a0, bA[nt], acc[0][nt], 0,0,0);
                    acc[1][nt] = __builtin_amdgcn_mfma_i32_16x16x64_i8(a1, bA[nt], acc[1][nt], 0,0,0);
                }
                const unsigned char* p2 = bp + (kt+2)*8192;
                #pragma unroll
                for (int nt=0;nt<8;++nt) bA[nt] = *(const int4v*)(p2 + nt*1024);
                a0 = *(const int4v*)(hr0 + (kt+1)*64 + lq*16);
                a1 = *(const int4v*)(hr1 + (kt+1)*64 + lq*16);
                #pragma unroll
                for (int nt=0;nt<8;++nt){
                    acc[0][nt] = __builtin_amdgcn_mfma_i32_16x16x64_i8(a0, bB[nt], acc[0][nt], 0,0,0);
                    acc[1][nt] = __builtin_amdgcn_mfma_i32_16x16x64_i8(a1, bB[nt], acc[1][nt], 0,0,0);
                }
            }
        }
        #pragma unroll
        for (int mf=0;mf<2;++mf)
            #pragma unroll
            for (int up=0;up<2;++up)
                #pragma unroll
                for (int r=0;r<4;++r){
                    int idx = (mf*2+up)*4 + r;
                    float gi = (float)acc[mf][0+up][r] * gs;
                    float gf = (float)acc[mf][2+up][r] * gs;
                    float gg = (float)acc[mf][4+up][r] * gs;
                    float go = (float)acc[mf][6+up][r] * gs;
                    float cn = sigf(gf)*cc[idx] + sigf(gi)*tanh_(gg);
                    cc[idx] = cn;
                    float h = sigf(go)*tanh_(cn);
                    hq[idx] = (int)rintf(h*127.f);
                }
    };

    const unsigned char* wsp = wpack;
    const unsigned char* wpp = wpack + (size_t)LSTR;
    const unsigned char* wdp = wpack + 2*(size_t)LSTR;

    // ---- speed encoder ----
    #pragma unroll 1
    for (int t=0;t<16;++t){
        int rb=t&1, wbuf=(t+1)&1;
        if (t<15 && tid<128){
            int m=tid>>2, f3=tid&3;
            float x = speed[((size_t)(row0+m)*16 + t+1)*4 + f3];
            int q = (int)rintf(fminf(fmaxf(x*31.75f,-127.f),127.f));
            unsigned char qb=(unsigned char)q;
            abuf[wbuf][m][512+f3]=qb; abuf[wbuf][m][516+f3]=qb; abuf[wbuf][m][520+f3]=qb; abuf[wbuf][m][524+f3]=qb;
        }
        step2(rb,wbuf,wsp,cc0,cc1,gs0, (t>0), (t<15));
        __syncthreads();
    }
    // ---- speed -> pos transition (final h_s in abuf[0]) ----
    for (int i=tid; i<MTILE*32; i+=NTHR){
        int m=i>>5, cb=(i&31)*16;
        *(int4v*)&hsave[m][cb] = *(const int4v*)&abuf[0][m][cb];
        *(int4v*)&abuf[0][m][cb] = (int4v){0,0,0,0};
    }
    #pragma unroll
    for (int s2=0;s2<2;++s2)
        #pragma unroll
        for (int mf=0;mf<2;++mf)
            #pragma unroll
            for (int up=0;up<2;++up)
                #pragma unroll
                for (int r=0;r<4;++r){
                    int idx=(mf*2+up)*4+r;
                    int ch=(2*wv+s2+cstag)&15;
                    csave[mf*16+lq*4+r][ch*32+up*16+l15] = s2 ? cc1[idx] : cc0[idx];
                }
    #pragma unroll
    for (int i=0;i<16;++i){ cc0[i]=0.f; cc1[i]=0.f; }
    if (tid < 128) {
        int m = tid>>2, f3 = tid&3;
        float x = pos[((size_t)(row0+m)*16 + 0)*4 + f3];
        int q = (int)rintf(fminf(fmaxf(x*31.75f,-127.f),127.f));
        unsigned char qb = (unsigned char)q;
        abuf[0][m][512+f3]=qb; abuf[0][m][516+f3]=qb; abuf[0][m][520+f3]=qb; abuf[0][m][524+f3]=qb;
    }
    __syncthreads();

    // ---- pos encoder ----
    #pragma unroll 1
    for (int t=0;t<16;++t){
        int rb=t&1, wbuf=(t+1)&1;
        if (t<15 && tid<128){
            int m=tid>>2, f3=tid&3;
            float x = pos[((size_t)(row0+m)*16 + t+1)*4 + f3];
            int q = (int)rintf(fminf(fmaxf(x*31.75f,-127.f),127.f));
            unsigned char qb=(unsigned char)q;
            abuf[wbuf][m][512+f3]=qb; abuf[wbuf][m][516+f3]=qb; abuf[wbuf][m][520+f3]=qb; abuf[wbuf][m][524+f3]=qb;
        }
        step2(rb,wbuf,wpp,cc0,cc1,gs1, (t>0), (t<15));
        __syncthreads();
    }
    // ---- combine: c += c_s; x=pos[:,15,:]; h_p in abuf[0], h_s in hsave ----
    if (tid < 128) {
        int m = tid>>2, f3 = tid&3;
        float x = pos[((size_t)(row0+m)*16 + 15)*4 + f3];
        int q = (int)rintf(fminf(fmaxf(x*31.75f,-127.f),127.f));
        unsigned char qb = (unsigned char)q;
        abuf[0][m][512+f3]=qb; abuf[0][m][516+f3]=qb; abuf[0][m][520+f3]=qb; abuf[0][m][524+f3]=qb;
    }
    #pragma unroll
    for (int s2=0;s2<2;++s2)
        #pragma unroll
        for (int mf=0;mf<2;++mf)
            #pragma unroll
            for (int up=0;up<2;++up)
                #pragma unroll
                for (int r=0;r<4;++r){
                    int idx=(mf*2+up)*4+r;
                    int ch=(2*wv+s2+cstag)&15;
                    float v = csave[mf*16+lq*4+r][ch*32+up*16+l15];
                    if (s2) cc1[idx]+=v; else cc0[idx]+=v;
                }
    __syncthreads();

    // ---- decoder ----
    #pragma unroll 1
    for (int t=0;t<16;++t){
        int hb;
        if (t == 0) {
            int hq0[16], hq1[16];
            pass_dual(wdp, 0, cc0, gs2, hq0);
            pass_dual(wdp, 1, cc1, gs2, hq1);
            __syncthreads();
            #pragma unroll
            for (int s2=0;s2<2;++s2)
                #pragma unroll
                for (int mf=0;mf<2;++mf)
                    #pragma unroll
                    for (int up=0;up<2;++up)
                        #pragma unroll
                        for (int r=0;r<4;++r){
                            int idx=(mf*2+up)*4+r;
                            int ch=(2*wv+s2+cstag)&15;
                            int q = s2 ? hq1[idx] : hq0[idx];
                            abuf[0][mf*16+lq*4+r][ch*32+up*16+l15] = (unsigned char)q;
                        }
            hb = 0;
        } else {
            int rb=(t+1)&1, wbuf=t&1;
            step2(rb,wbuf,wdp,cc0,cc1,gs2, (t>1), (t<15));
            hb = wbuf;
        }
        __syncthreads();
        {   // crossing partials: wave wv covers k-slice [wv*64, wv*64+64)
            int r = lane>>1, col = lane&1;
            const unsigned char* hp = &abuf[hb][r][wv*64];
            const float* wp = &smallw[col*512 + wv*64];
            float p = 0.f;
            #pragma unroll
            for (int k4=0;k4<16;++k4){
                int v = *(const int*)(hp + k4*4);
                p += (float)((signed char)(v    )) * wp[k4*4+0];
                p += (float)((signed char)(v>>8 )) * wp[k4*4+1];
                p += (float)((signed char)(v>>16)) * wp[k4*4+2];
                p += (float)((signed char)(v>>24)) * wp[k4*4+3];
            }
            partial[wv*64 + lane] = p;
        }
        __syncthreads();
        if (wv == 0) {
            float p = 0.f;
            #pragma unroll
            for (int i=0;i<8;++i) p += partial[i*64 + lane];
            int r = lane>>1, col = lane&1;
            p = p*(1.f/127.f) + smallw[1024+col];
            float cr = fmaxf(p, 0.f);
            float other = __shfl_xor(cr, 1, 64);
            float mx = fmaxf(cr, other);
            float e0 = ex2(LOG2E*(cr-mx)), e1 = ex2(LOG2E*(other-mx));
            out[((size_t)(row0+r))*32 + t*2 + col] = e0*rcpn(e0+e1);
            float c0v = col ? other : cr;
            float c1v = col ? cr : other;
            #pragma unroll
            for (int q2=0;q2<2;++q2){
                int e = col*2 + q2;
                float lp = fmaxf(c0v*smallw[1026+e*2] + c1v*smallw[1026+e*2+1] + smallw[1034+e], 0.f);
                int qv = (int)rintf(fminf(lp*31.75f, 127.f));
                unsigned char qb = (unsigned char)qv;
                abuf[hb][r][512+e]=qb; abuf[hb][r][516+e]=qb; abuf[hb][r][520+e]=qb; abuf[hb][r][524+e]=qb;
            }
        }
        __syncthreads();
    }
}

extern "C" void kernel_launch(void* const* d_in, const int* in_sizes, int n_in,
                              void* d_out, int out_size, void* d_ws, size_t ws_size,
                              hipStream_t stream)
{
    (void)in_sizes; (void)n_in; (void)out_size; (void)ws_size;
    const float* speed = (const float*)d_in[0];
    const float* pos   = (const float*)d_in[1];
    const float* Ws_ih = (const float*)d_in[2];
    const float* Ws_hh = (const float*)d_in[3];
    const float* bs_ih = (const float*)d_in[4];
    const float* bs_hh = (const float*)d_in[5];
    const float* Wp_ih = (const float*)d_in[6];
    const float* Wp_hh = (const float*)d_in[7];
    const float* bp_ih = (const float*)d_in[8];
    const float* bp_hh = (const float*)d_in[9];
    const float* Wd_ih = (const float*)d_in[10];
    const float* Wd_hh = (const float*)d_in[11];
    const float* bd_ih = (const float*)d_in[12];
    const float* bd_hh = (const float*)d_in[13];
    const float* W_fc  = (const float*)d_in[14];
    const float* b_fc  = (const float*)d_in[15];
    const float* W_emb = (const float*)d_in[16];
    const float* b_emb = (const float*)d_in[17];

    unsigned char* wp8 = (unsigned char*)d_ws;
    int*   smax  = (int*)(wp8 + 3*(size_t)LSTR);
    float* gsout = (float*)(wp8 + 3*(size_t)LSTR + 16);

    scale_k<<<96, 256, 0, stream>>>(Ws_ih,Ws_hh,bs_ih,bs_hh, Wp_ih,Wp_hh,bp_ih,bp_hh,
                                    Wd_ih,Wd_hh,bd_ih,bd_hh, smax);
    int gb = (LSTR/4 + 255) / 256;
    pack_k<<<gb, 256, 0, stream>>>(Ws_ih, Ws_hh, bs_ih, bs_hh, smax, 0, wp8,                  gsout);
    pack_k<<<gb, 256, 0, stream>>>(Wp_ih, Wp_hh, bp_ih, bp_hh, smax, 1, wp8 +   (size_t)LSTR, gsout);
    pack_k<<<gb, 256, 0, stream>>>(Wd_ih, Wd_hh, bd_ih, bd_hh, smax, 2, wp8 + 2*(size_t)LSTR, gsout);
    lstm_all<<<NBLK, NTHR, 0, stream>>>(speed, pos, wp8, gsout,
                                        W_fc, b_fc, W_emb, b_emb, (float*)d_out);
}